// Round 4
// baseline (695.822 us; speedup 1.0000x reference)
//
#include <hip/hip_runtime.h>

typedef unsigned short u16;
typedef __attribute__((ext_vector_type(4))) short s16x4;
typedef __attribute__((ext_vector_type(8))) short s16x8;
typedef __attribute__((ext_vector_type(4))) float f32x4;

#define MFMA16(a,b,c) __builtin_amdgcn_mfma_f32_16x16x32_bf16((a),(b),(c),0,0,0)
#define LSEQ 2048
#define QSCALE 0.18033688011112042f  /* 0.125 * log2(e) */

__device__ __forceinline__ u16 f2b(float f) {
  union { float f; unsigned u; } v; v.f = f;
  unsigned r = v.u + 0x7FFFu + ((v.u >> 16) & 1u);
  return (u16)(r >> 16);
}
__device__ __forceinline__ u16 f2b_fast(float f) {
  union { float f; unsigned u; } v; v.f = f;
  return (u16)((v.u + 0x8000u) >> 16);
}
__device__ __forceinline__ unsigned pk2(float a, float b) {
  return (unsigned)f2b_fast(a) | ((unsigned)f2b_fast(b) << 16);
}
__device__ __forceinline__ void g2l16(const void* g, void* l) {
  __builtin_amdgcn_global_load_lds(
      (const __attribute__((address_space(1))) unsigned int*)g,
      (__attribute__((address_space(3))) unsigned int*)l, 16, 0, 0);
}

// ---------------- convert f32 -> bf16, 4 elems/thread ----------------
__global__ __launch_bounds__(256) void k_cvt(const float* __restrict__ in, u16* __restrict__ out, int n) {
  int i = (blockIdx.x * 256 + threadIdx.x) * 4;
  if (i + 3 < n) {
    float4 v = *(const float4*)(in + i);
    ushort4 o;
    o.x = f2b(v.x); o.y = f2b(v.y); o.z = f2b(v.z); o.w = f2b(v.w);
    *(ushort4*)(out + i) = o;
  }
}

// ---------------- bias concat ----------------
__global__ __launch_bounds__(256) void k_prep(const float* __restrict__ bq, const float* __restrict__ bk,
                                              const float* __restrict__ bv, float* __restrict__ bcat) {
  int i = blockIdx.x * 256 + threadIdx.x;
  if (i < 1024) bcat[i] = bq[i];
  else if (i < 2048) bcat[i] = bk[i - 1024];
  else if (i < 3072) bcat[i] = bv[i - 2048];
}

// ------------- transpose+convert: W[K,N] f32 -> Wt[N,K] bf16 -------------
__global__ __launch_bounds__(256) void k_transpose(const float* __restrict__ W, u16* __restrict__ Wt, int K, int N) {
  __shared__ float T[64][65];
  int k0 = blockIdx.y * 64, n0 = blockIdx.x * 64;
  int r = threadIdx.x >> 4;
  int c4 = (threadIdx.x & 15) * 4;
#pragma unroll
  for (int i = 0; i < 4; i++) {
    float4 v = *(const float4*)(W + (size_t)(k0 + r + i * 16) * N + n0 + c4);
    T[r + i * 16][c4 + 0] = v.x; T[r + i * 16][c4 + 1] = v.y;
    T[r + i * 16][c4 + 2] = v.z; T[r + i * 16][c4 + 3] = v.w;
  }
  __syncthreads();
#pragma unroll
  for (int i = 0; i < 4; i++) {
    int nl = r + i * 16;
    ushort4 o;
    o.x = f2b(T[c4 + 0][nl]); o.y = f2b(T[c4 + 1][nl]);
    o.z = f2b(T[c4 + 2][nl]); o.w = f2b(T[c4 + 3][nl]);
    *(ushort4*)(Wt + (size_t)(n0 + nl) * K + k0 + c4) = o;
  }
}

// ------------- bf16 MFMA GEMM, gload_lds dbuf, swizzled LDS -------------
// C[M,N] = A[M,K] @ Bt[N,K]^T + bias.  FLAGS: 1=RELU, 2=BF16OUT, 4=QKV, 8=RESID(f32 out)
template <int BN, int FLAGS>
__global__ __launch_bounds__(256) void k_gemm(const u16* __restrict__ A, const u16* __restrict__ Bt,
                                              const float* __restrict__ bias, const float* __restrict__ resid,
                                              void* __restrict__ Cout, int M, int N, int K) {
  constexpr int MI = (BN == 128) ? 4 : 2;
  __shared__ __align__(16) u16 As[2][128 * 32];
  __shared__ __align__(16) u16 Bs[2][BN * 32];
  const int tid = threadIdx.x;
  const int lane = tid & 63, wave = tid >> 6;
  const int lo = lane & 15, hi = lane >> 4;
  const int WROW = (BN == 128) ? (wave >> 1) * 64 : wave * 32;
  const int WCOL = (BN == 128) ? (wave & 1) * 64 : 0;
  const int m0 = blockIdx.y * 128, n0 = blockIdx.x * BN;

  const int colg = ((lane & 3) * 16) ^ (((lane >> 3) & 3) << 4);
  const int arow = wave * 32 + (lane >> 2);
  const int swzr = ((lane >> 1) & 3) << 4;

  f32x4 acc[MI][4];
#pragma unroll
  for (int mi = 0; mi < MI; mi++)
#pragma unroll
    for (int ni = 0; ni < 4; ni++) acc[mi][ni] = (f32x4){0.f, 0.f, 0.f, 0.f};

  const char* Ab = (const char*)A;
  const char* Bb = (const char*)Bt;
  const int nt = K >> 5;

  auto stage = [&](int buf, int t) {
    const int k0 = t * 32;
    char* ad = (char*)&As[buf][0] + wave * 2048;
    const char* as = Ab + ((size_t)(m0 + arow) * K + k0) * 2 + colg;
    g2l16(as, ad);
    g2l16(as + (size_t)16 * K * 2, ad + 1024);
    if (BN == 128) {
      char* bd = (char*)&Bs[buf][0] + wave * 2048;
      const char* bs = Bb + ((size_t)(n0 + arow) * K + k0) * 2 + colg;
      g2l16(bs, bd);
      g2l16(bs + (size_t)16 * K * 2, bd + 1024);
    } else {
      char* bd = (char*)&Bs[buf][0] + wave * 1024;
      const int brow = wave * 16 + (lane >> 2);
      const char* bs = Bb + ((size_t)(n0 + brow) * K + k0) * 2 + colg;
      g2l16(bs, bd);
    }
  };

  stage(0, 0);
  int buf = 0;
  for (int t = 0; t < nt; t++) {
    __syncthreads();
    if (t + 1 < nt) stage(buf ^ 1, t + 1);
    const char* ab = (const char*)&As[buf][0];
    const char* bb2 = (const char*)&Bs[buf][0];
    s16x8 af[MI], bfr[4];
#pragma unroll
    for (int mi = 0; mi < MI; mi++) {
      int row = WROW + mi * 16 + lo;
      af[mi] = *(const s16x8*)(ab + row * 64 + ((hi * 16) ^ swzr));
    }
#pragma unroll
    for (int ni = 0; ni < 4; ni++) {
      int row = WCOL + ni * 16 + lo;
      bfr[ni] = *(const s16x8*)(bb2 + row * 64 + ((hi * 16) ^ swzr));
    }
#pragma unroll
    for (int mi = 0; mi < MI; mi++)
#pragma unroll
      for (int ni = 0; ni < 4; ni++)
        acc[mi][ni] = MFMA16(af[mi], bfr[ni], acc[mi][ni]);
    buf ^= 1;
  }

#pragma unroll
  for (int mi = 0; mi < MI; mi++)
#pragma unroll
    for (int ni = 0; ni < 4; ni++) {
      const int mb = m0 + WROW + mi * 16 + hi * 4;
      const int n = n0 + WCOL + ni * 16 + lo;
      float v4[4];
#pragma unroll
      for (int reg = 0; reg < 4; reg++) {
        float v = acc[mi][ni][reg] + bias[n];
        if (FLAGS & 8) v += resid[(size_t)(mb + reg) * N + n];
        if (FLAGS & 1) v = fmaxf(v, 0.f);
        v4[reg] = v;
      }
      if (FLAGS & 4) {
        const int seg = n >> 10, nn = n & 1023;
        const int hh = nn >> 6, dd = nn & 63;
        const int bb = mb >> 11, ll = mb & 2047;
        u16* dst = (u16*)Cout + (size_t)seg * 4194304;
        if (seg == 0) {
#pragma unroll
          for (int reg = 0; reg < 4; reg++)
            dst[((size_t)(bb * 16 + hh) * LSEQ + ll + reg) * 64 + dd] = f2b(v4[reg] * QSCALE);
        } else if (seg == 1) {
#pragma unroll
          for (int reg = 0; reg < 4; reg++)
            dst[((size_t)(bb * 16 + hh) * LSEQ + ll + reg) * 64 + dd] = f2b(v4[reg]);
        } else {
          ushort4 o;
          o.x = f2b(v4[0]); o.y = f2b(v4[1]); o.z = f2b(v4[2]); o.w = f2b(v4[3]);
          *(ushort4*)&((u16*)dst)[((size_t)(bb * 16 + hh) * 64 + dd) * LSEQ + ll] = o;
        }
      } else if (FLAGS & 2) {
        u16* dst = (u16*)Cout;
#pragma unroll
        for (int reg = 0; reg < 4; reg++) dst[(size_t)(mb + reg) * N + n] = f2b(v4[reg]);
      } else {
        float* dst = (float*)Cout;
#pragma unroll
        for (int reg = 0; reg < 4; reg++) dst[(size_t)(mb + reg) * N + n] = v4[reg];
      }
    }
}

// ------------- fused rel-pos flash attention, transposed (S^T) dataflow -------------
// Qh/Kh = [B*H, L, 64] bf16; Vt = [B*H, 64, L] bf16; Ob = [B*L, 1024] bf16.
// Each lane owns ONE query row (lo); softmax is in-lane; P feeds PV in-register via
// a k-slot permutation applied identically to P (B-op) and V^T (A-op). No __syncthreads.
__global__ __launch_bounds__(256) void k_attn(const u16* __restrict__ Qh, const u16* __restrict__ Kh,
                                              const u16* __restrict__ Vt, const u16* __restrict__ Eb,
                                              u16* __restrict__ Ob) {
  __shared__ __align__(16) float Gsh[4][16 * 84];  // per-wave skew-gather buffer [lo][84]

  const int tid = threadIdx.x;
  const int lane = tid & 63, wave = tid >> 6;
  const int lo = lane & 15, hi = lane >> 4;

  // XCD-chunked mapping: XCD c owns heads [4c, 4c+4)
  const int hb = blockIdx.x;
  const int logical = (hb & 7) * 128 + (hb >> 3);
  const int bh = logical >> 5;
  const int l0 = (logical & 31) * 64;
  const int bb = bh >> 4, hh = bh & 15;
  const int lw = l0 + wave * 16;

  const u16* Qb = Qh + (size_t)bh * LSEQ * 64;
  const u16* Kb = Kh + (size_t)bh * LSEQ * 64;
  const u16* Vb = Vt + (size_t)bh * 64 * LSEQ;

  // Q as B-operand: col=lo -> query lw+lo, k = 32*half + hi*8 + e
  s16x8 aq[2];
  aq[0] = *(const s16x8*)(Qb + (size_t)(lw + lo) * 64 + hi * 8);
  aq[1] = *(const s16x8*)(Qb + (size_t)(lw + lo) * 64 + 32 + hi * 8);

  float m_run = -1e30f, l_run = 0.f;
  f32x4 oacc[4];
#pragma unroll
  for (int f = 0; f < 4; f++) oacc[f] = (f32x4){0.f, 0.f, 0.f, 0.f};

  float* gw = &Gsh[wave][0];

  // K A-frags for tile 0: A[row=lo]=K[j0+c*16+lo][d=32*half+hi*8+e]
  s16x8 kc[4][2];
#pragma unroll
  for (int c = 0; c < 4; c++)
#pragma unroll
    for (int half = 0; half < 2; half++)
      kc[c][half] = *(const s16x8*)(Kb + (size_t)(c * 16 + lo) * 64 + half * 32 + hi * 8);

  for (int t = 0; t < 32; t++) {
    const int j0 = t * 64;

    // --- V for current tile: A-frag with permuted k-slots: e<4 -> j0+32h+4hi+e, e>=4 -> +16
    s16x4 vA[4][2], vBv[4][2];
#pragma unroll
    for (int f = 0; f < 4; f++)
#pragma unroll
      for (int h = 0; h < 2; h++) {
        const u16* vp = Vb + (size_t)(f * 16 + lo) * LSEQ + j0 + 32 * h + 4 * hi;
        vA[f][h] = *(const s16x4*)vp;
        vBv[f][h] = *(const s16x4*)(vp + 16);
      }

    // --- K for next tile (register double-buffer)
    s16x8 kn[4][2];
    if (t < 31) {
#pragma unroll
      for (int c = 0; c < 4; c++)
#pragma unroll
        for (int half = 0; half < 2; half++)
          kn[c][half] = *(const s16x8*)(Kb + (size_t)(j0 + 64 + c * 16 + lo) * 64 + half * 32 + hi * 8);
    }

    const bool has_rel = (j0 <= l0);
    const int waveBase = 2032 - lw + j0;

    // --- E A-frags (L1/L2-hot; OOB rows land in allocated ws, masked before add)
    s16x8 e0[5], e1[5];
    if (has_rel) {
#pragma unroll
      for (int c2 = 0; c2 < 5; c2++) {
        const u16* ep = Eb + (size_t)(waveBase + c2 * 16 + lo) * 64;
        e0[c2] = *(const s16x8*)(ep + hi * 8);
        e1[c2] = *(const s16x8*)(ep + 32 + hi * 8);
      }
    }

    // --- S^T = mfma(K, Q): s4[c][reg] = S[j_rel=c*16+4hi+reg][q=lo]
    f32x4 s4[4];
#pragma unroll
    for (int c = 0; c < 4; c++) {
      s4[c] = (f32x4){0.f, 0.f, 0.f, 0.f};
      s4[c] = MFMA16(kc[c][0], aq[0], s4[c]);
      s4[c] = MFMA16(kc[c][1], aq[1], s4[c]);
    }

    // --- rel: G^T band via mfma(E, Q), skew-gather through per-wave LDS
    if (has_rel) {
#pragma unroll
      for (int c2 = 0; c2 < 5; c2++) {
        f32x4 g = (f32x4){0.f, 0.f, 0.f, 0.f};
        g = MFMA16(e0[c2], aq[0], g);
        g = MFMA16(e1[c2], aq[1], g);
        *(f32x4*)(gw + 84 * lo + c2 * 16 + 4 * hi) = g;  // ds_write_b128
      }
      if (j0 < l0) {  // fully below diagonal: every position valid
#pragma unroll
        for (int c = 0; c < 4; c++)
#pragma unroll
          for (int reg = 0; reg < 4; reg++)
            s4[c][reg] += gw[83 * lo + c * 16 + 4 * hi + reg + 15];
      } else {  // diagonal tile: mask j_rel - lo <= 16*wave
        const int rmax = 16 * wave + lo;
#pragma unroll
        for (int c = 0; c < 4; c++)
#pragma unroll
          for (int reg = 0; reg < 4; reg++) {
            int jr = c * 16 + 4 * hi + reg;
            float g = gw[83 * lo + jr + 15];
            s4[c][reg] += (jr <= rmax) ? g : 0.f;
          }
      }
    }

    // --- in-lane softmax (base-2): one query row per lane
    float mt = s4[0][0];
#pragma unroll
    for (int c = 0; c < 4; c++)
#pragma unroll
      for (int reg = 0; reg < 4; reg++) mt = fmaxf(mt, s4[c][reg]);
    mt = fmaxf(mt, __shfl_xor(mt, 16, 64));
    mt = fmaxf(mt, __shfl_xor(mt, 32, 64));
    float mnew = fmaxf(m_run, mt);
    float scl = exp2f(m_run - mnew);
    m_run = mnew;

    float p[4][4];
    float psum = 0.f;
#pragma unroll
    for (int c = 0; c < 4; c++)
#pragma unroll
      for (int reg = 0; reg < 4; reg++) {
        float pv = exp2f(s4[c][reg] - mnew);
        p[c][reg] = pv;
        psum += pv;
      }

    // rescale O before accumulating this tile
#pragma unroll
    for (int f = 0; f < 4; f++)
#pragma unroll
      for (int reg = 0; reg < 4; reg++) oacc[f][reg] *= scl;

    // --- pack P into B-frags matching the k-slot permutation
    union UU { uint4 u; s16x8 v; };
    UU pb0, pb1;
    pb0.u = make_uint4(pk2(p[0][0], p[0][1]), pk2(p[0][2], p[0][3]),
                       pk2(p[1][0], p[1][1]), pk2(p[1][2], p[1][3]));
    pb1.u = make_uint4(pk2(p[2][0], p[2][1]), pk2(p[2][2], p[2][3]),
                       pk2(p[3][0], p[3][1]), pk2(p[3][2], p[3][3]));

    // --- O^T += V^T · P : A-frag = concat(vA, vBv)
#pragma unroll
    for (int f = 0; f < 4; f++) {
      s16x8 v0 = __builtin_shufflevector(vA[f][0], vBv[f][0], 0, 1, 2, 3, 4, 5, 6, 7);
      s16x8 v1 = __builtin_shufflevector(vA[f][1], vBv[f][1], 0, 1, 2, 3, 4, 5, 6, 7);
      oacc[f] = MFMA16(v0, pb0.v, oacc[f]);
      oacc[f] = MFMA16(v1, pb1.v, oacc[f]);
    }

    // psum cross-lane reduce (overlaps PV)
    psum += __shfl_xor(psum, 16, 64);
    psum += __shfl_xor(psum, 32, 64);
    l_run = l_run * scl + psum;

    if (t < 31) {
#pragma unroll
      for (int c = 0; c < 4; c++)
#pragma unroll
        for (int half = 0; half < 2; half++) kc[c][half] = kn[c][half];
    }
  }

  const float inv = 1.f / l_run;
  const size_t orow = (size_t)(bb * LSEQ + lw + lo) * 1024 + hh * 64;
#pragma unroll
  for (int f = 0; f < 4; f++) {
    ushort4 o;
    o.x = f2b(oacc[f][0] * inv); o.y = f2b(oacc[f][1] * inv);
    o.z = f2b(oacc[f][2] * inv); o.w = f2b(oacc[f][3] * inv);
    *(ushort4*)(Ob + orow + f * 16 + 4 * hi) = o;
  }
}

// ------------- LayerNorm over rows of 1024, optional bf16 copy -------------
__global__ __launch_bounds__(256) void k_layernorm(const float* __restrict__ X, const float* __restrict__ gw,
                                                   const float* __restrict__ bw, float* __restrict__ outF,
                                                   u16* __restrict__ outB) {
  __shared__ float red[2][4];
  const int row = blockIdx.x, tid = threadIdx.x;
  const int lane = tid & 63, wave = tid >> 6;
  const float* x = X + (size_t)row * 1024;
  float4 v = *(const float4*)(x + tid * 4);
  float s = v.x + v.y + v.z + v.w;
  float s2 = v.x * v.x + v.y * v.y + v.z * v.z + v.w * v.w;
#pragma unroll
  for (int msk = 1; msk <= 32; msk <<= 1) {
    s += __shfl_xor(s, msk, 64);
    s2 += __shfl_xor(s2, msk, 64);
  }
  if (lane == 0) { red[0][wave] = s; red[1][wave] = s2; }
  __syncthreads();
  s = red[0][0] + red[0][1] + red[0][2] + red[0][3];
  s2 = red[1][0] + red[1][1] + red[1][2] + red[1][3];
  float mean = s * (1.f / 1024.f);
  float var = s2 * (1.f / 1024.f) - mean * mean;
  float rs = rsqrtf(var + 1e-6f);
  float4 g4 = *(const float4*)(gw + tid * 4);
  float4 b4 = *(const float4*)(bw + tid * 4);
  float4 o;
  o.x = (v.x - mean) * rs * g4.x + b4.x;
  o.y = (v.y - mean) * rs * g4.y + b4.y;
  o.z = (v.z - mean) * rs * g4.z + b4.z;
  o.w = (v.w - mean) * rs * g4.w + b4.w;
  *(float4*)(outF + (size_t)row * 1024 + tid * 4) = o;
  if (outB) {
    ushort4 ob;
    ob.x = f2b(o.x); ob.y = f2b(o.y); ob.z = f2b(o.z); ob.w = f2b(o.w);
    *(ushort4*)(outB + (size_t)row * 1024 + tid * 4) = ob;
  }
}

extern "C" void kernel_launch(void* const* d_in, const int* in_sizes, int n_in,
                              void* d_out, int out_size, void* d_ws, size_t ws_size,
                              hipStream_t stream) {
  const float* x   = (const float*)d_in[0];
  const float* Wq  = (const float*)d_in[1];
  const float* bq  = (const float*)d_in[2];
  const float* Wk  = (const float*)d_in[3];
  const float* bk  = (const float*)d_in[4];
  const float* Wv  = (const float*)d_in[5];
  const float* bv  = (const float*)d_in[6];
  const float* Wo  = (const float*)d_in[7];
  const float* bo  = (const float*)d_in[8];
  const float* E   = (const float*)d_in[9];
  const float* W1  = (const float*)d_in[10];
  const float* b1  = (const float*)d_in[11];
  const float* W2  = (const float*)d_in[12];
  const float* b2  = (const float*)d_in[13];
  const float* g1  = (const float*)d_in[14];
  const float* be1 = (const float*)d_in[15];
  const float* g2  = (const float*)d_in[16];
  const float* be2 = (const float*)d_in[17];

  char* ws = (char*)d_ws;
  const size_t MB = 1ull << 20;
  u16* Wqt = (u16*)(ws + 0 * MB);          // 6MB contiguous [3072][1024] (Wq/Wk/Wv)
  u16* Wkt = (u16*)(ws + 2 * MB);
  u16* Wvt = (u16*)(ws + 4 * MB);
  u16* Wot = (u16*)(ws + 6 * MB);          // 2MB
  u16* W1t = (u16*)(ws + 8 * MB);          // 8MB [4096][1024]
  u16* W2t = (u16*)(ws + 16 * MB);         // 8MB [1024][4096]
  u16* Ebf = (u16*)(ws + 24 * MB);         // 256KB [2048][64]
  float* bcat = (float*)(ws + 24 * MB + 512 * 1024);  // 12KB
  u16* xb  = (u16*)(ws + 25 * MB);         // 8MB [4096][1024]
  u16* qb  = (u16*)(ws + 33 * MB);         // 8MB head-major (QSCALE'd)
  u16* kb  = (u16*)(ws + 41 * MB);         // 8MB head-major
  u16* vt  = (u16*)(ws + 49 * MB);         // 8MB transposed [bh][64][L]
  u16* ao  = (u16*)(ws + 57 * MB);         // 8MB [4096][1024]
  float* t1 = (float*)(ws + 65 * MB);      // 16MB f32
  u16* o1b  = (u16*)(ws + 25 * MB);        // reuse xb
  float* o1f = (float*)(ws + 33 * MB);     // reuse qb/kb
  u16* h1b  = (u16*)(ws + 49 * MB);        // reuse vt/ao/t1, 32MB [4096][4096]
  float* outF = (float*)d_out;

  // 1) conversions / prep
  k_cvt<<<4096, 256, 0, stream>>>(x, xb, 4096 * 1024);
  k_cvt<<<128, 256, 0, stream>>>(E, Ebf, 2048 * 64);
  k_prep<<<12, 256, 0, stream>>>(bq, bk, bv, bcat);
  k_transpose<<<dim3(16, 16), 256, 0, stream>>>(Wq, Wqt, 1024, 1024);
  k_transpose<<<dim3(16, 16), 256, 0, stream>>>(Wk, Wkt, 1024, 1024);
  k_transpose<<<dim3(16, 16), 256, 0, stream>>>(Wv, Wvt, 1024, 1024);
  k_transpose<<<dim3(16, 16), 256, 0, stream>>>(Wo, Wot, 1024, 1024);
  k_transpose<<<dim3(64, 16), 256, 0, stream>>>(W1, W1t, 1024, 4096);
  k_transpose<<<dim3(16, 64), 256, 0, stream>>>(W2, W2t, 4096, 1024);

  // 2) fused QKV projection (writes qb, kb, vt)
  k_gemm<128, 4><<<dim3(24, 32), 256, 0, stream>>>(xb, Wqt, bcat, nullptr, qb, 4096, 3072, 1024);

  // 3) rel-pos flash attention -> ao
  k_attn<<<dim3(1024), 256, 0, stream>>>(qb, kb, vt, Ebf, ao);

  // 4) O-proj + residual(x) -> t1 f32
  k_gemm<64, 8><<<dim3(16, 32), 256, 0, stream>>>(ao, Wot, bo, x, t1, 4096, 1024, 1024);

  // 5) LN1 -> o1f (f32) + o1b (bf16)
  k_layernorm<<<4096, 256, 0, stream>>>(t1, g1, be1, o1f, o1b);

  // 6) FFN1: relu(out1 @ W1 + b1) -> h1b bf16
  k_gemm<128, 3><<<dim3(32, 32), 256, 0, stream>>>(o1b, W1t, b1, nullptr, h1b, 4096, 4096, 1024);

  // 7) FFN2 + residual(o1f) -> d_out f32
  k_gemm<64, 8><<<dim3(16, 32), 256, 0, stream>>>(h1b, W2t, b2, o1f, outF, 4096, 1024, 4096);

  // 8) LN2 in-place on d_out
  k_layernorm<<<4096, 256, 0, stream>>>(outF, g2, be2, outF, nullptr);
}

// Round 5
// 542.232 us; speedup vs baseline: 1.2833x; 1.2833x over previous
//
#include <hip/hip_runtime.h>

typedef unsigned short u16;
typedef __attribute__((ext_vector_type(4))) short s16x4;
typedef __attribute__((ext_vector_type(8))) short s16x8;
typedef __attribute__((ext_vector_type(4))) float f32x4;

#define MFMA16(a,b,c) __builtin_amdgcn_mfma_f32_16x16x32_bf16((a),(b),(c),0,0,0)
#define LSEQ 2048
#define QSCALE 0.18033688011112042f  /* 0.125 * log2(e) */

__device__ __forceinline__ u16 f2b(float f) {
  union { float f; unsigned u; } v; v.f = f;
  unsigned r = v.u + 0x7FFFu + ((v.u >> 16) & 1u);
  return (u16)(r >> 16);
}
__device__ __forceinline__ u16 f2b_fast(float f) {
  union { float f; unsigned u; } v; v.f = f;
  return (u16)((v.u + 0x8000u) >> 16);
}
__device__ __forceinline__ unsigned pk2(float a, float b) {
  return (unsigned)f2b_fast(a) | ((unsigned)f2b_fast(b) << 16);
}
__device__ __forceinline__ void g2l16(const void* g, void* l) {
  __builtin_amdgcn_global_load_lds(
      (const __attribute__((address_space(1))) unsigned int*)g,
      (__attribute__((address_space(3))) unsigned int*)l, 16, 0, 0);
}

// ---------------- convert f32 -> bf16, 4 elems/thread ----------------
__global__ __launch_bounds__(256) void k_cvt(const float* __restrict__ in, u16* __restrict__ out, int n) {
  int i = (blockIdx.x * 256 + threadIdx.x) * 4;
  if (i + 3 < n) {
    float4 v = *(const float4*)(in + i);
    ushort4 o;
    o.x = f2b(v.x); o.y = f2b(v.y); o.z = f2b(v.z); o.w = f2b(v.w);
    *(ushort4*)(out + i) = o;
  }
}

// ---------------- bias concat ----------------
__global__ __launch_bounds__(256) void k_prep(const float* __restrict__ bq, const float* __restrict__ bk,
                                              const float* __restrict__ bv, float* __restrict__ bcat) {
  int i = blockIdx.x * 256 + threadIdx.x;
  if (i < 1024) bcat[i] = bq[i];
  else if (i < 2048) bcat[i] = bk[i - 1024];
  else if (i < 3072) bcat[i] = bv[i - 2048];
}

// ------------- transpose+convert: W[K,N] f32 -> Wt[N,K] bf16 -------------
__global__ __launch_bounds__(256) void k_transpose(const float* __restrict__ W, u16* __restrict__ Wt, int K, int N) {
  __shared__ float T[64][65];
  int k0 = blockIdx.y * 64, n0 = blockIdx.x * 64;
  int r = threadIdx.x >> 4;
  int c4 = (threadIdx.x & 15) * 4;
#pragma unroll
  for (int i = 0; i < 4; i++) {
    float4 v = *(const float4*)(W + (size_t)(k0 + r + i * 16) * N + n0 + c4);
    T[r + i * 16][c4 + 0] = v.x; T[r + i * 16][c4 + 1] = v.y;
    T[r + i * 16][c4 + 2] = v.z; T[r + i * 16][c4 + 3] = v.w;
  }
  __syncthreads();
#pragma unroll
  for (int i = 0; i < 4; i++) {
    int nl = r + i * 16;
    ushort4 o;
    o.x = f2b(T[c4 + 0][nl]); o.y = f2b(T[c4 + 1][nl]);
    o.z = f2b(T[c4 + 2][nl]); o.w = f2b(T[c4 + 3][nl]);
    *(ushort4*)(Wt + (size_t)(n0 + nl) * K + k0 + c4) = o;
  }
}

// ------------- bf16 MFMA GEMM, gload_lds dbuf, swizzled LDS -------------
// C[M,N] = A[M,K] @ Bt[N,K]^T + bias.  FLAGS: 1=RELU, 2=BF16OUT, 4=QKV, 8=RESID(f32 out)
template <int BN, int FLAGS>
__global__ __launch_bounds__(256) void k_gemm(const u16* __restrict__ A, const u16* __restrict__ Bt,
                                              const float* __restrict__ bias, const float* __restrict__ resid,
                                              void* __restrict__ Cout, int M, int N, int K) {
  constexpr int MI = (BN == 128) ? 4 : 2;
  __shared__ __align__(16) u16 As[2][128 * 32];
  __shared__ __align__(16) u16 Bs[2][BN * 32];
  const int tid = threadIdx.x;
  const int lane = tid & 63, wave = tid >> 6;
  const int lo = lane & 15, hi = lane >> 4;
  const int WROW = (BN == 128) ? (wave >> 1) * 64 : wave * 32;
  const int WCOL = (BN == 128) ? (wave & 1) * 64 : 0;
  const int m0 = blockIdx.y * 128, n0 = blockIdx.x * BN;

  const int colg = ((lane & 3) * 16) ^ (((lane >> 3) & 3) << 4);
  const int arow = wave * 32 + (lane >> 2);
  const int swzr = ((lane >> 1) & 3) << 4;

  f32x4 acc[MI][4];
#pragma unroll
  for (int mi = 0; mi < MI; mi++)
#pragma unroll
    for (int ni = 0; ni < 4; ni++) acc[mi][ni] = (f32x4){0.f, 0.f, 0.f, 0.f};

  const char* Ab = (const char*)A;
  const char* Bb = (const char*)Bt;
  const int nt = K >> 5;

  auto stage = [&](int buf, int t) {
    const int k0 = t * 32;
    char* ad = (char*)&As[buf][0] + wave * 2048;
    const char* as = Ab + ((size_t)(m0 + arow) * K + k0) * 2 + colg;
    g2l16(as, ad);
    g2l16(as + (size_t)16 * K * 2, ad + 1024);
    if (BN == 128) {
      char* bd = (char*)&Bs[buf][0] + wave * 2048;
      const char* bs = Bb + ((size_t)(n0 + arow) * K + k0) * 2 + colg;
      g2l16(bs, bd);
      g2l16(bs + (size_t)16 * K * 2, bd + 1024);
    } else {
      char* bd = (char*)&Bs[buf][0] + wave * 1024;
      const int brow = wave * 16 + (lane >> 2);
      const char* bs = Bb + ((size_t)(n0 + brow) * K + k0) * 2 + colg;
      g2l16(bs, bd);
    }
  };

  stage(0, 0);
  int buf = 0;
  for (int t = 0; t < nt; t++) {
    __syncthreads();
    if (t + 1 < nt) stage(buf ^ 1, t + 1);
    const char* ab = (const char*)&As[buf][0];
    const char* bb2 = (const char*)&Bs[buf][0];
    s16x8 af[MI], bfr[4];
#pragma unroll
    for (int mi = 0; mi < MI; mi++) {
      int row = WROW + mi * 16 + lo;
      af[mi] = *(const s16x8*)(ab + row * 64 + ((hi * 16) ^ swzr));
    }
#pragma unroll
    for (int ni = 0; ni < 4; ni++) {
      int row = WCOL + ni * 16 + lo;
      bfr[ni] = *(const s16x8*)(bb2 + row * 64 + ((hi * 16) ^ swzr));
    }
#pragma unroll
    for (int mi = 0; mi < MI; mi++)
#pragma unroll
      for (int ni = 0; ni < 4; ni++)
        acc[mi][ni] = MFMA16(af[mi], bfr[ni], acc[mi][ni]);
    buf ^= 1;
  }

#pragma unroll
  for (int mi = 0; mi < MI; mi++)
#pragma unroll
    for (int ni = 0; ni < 4; ni++) {
      const int mb = m0 + WROW + mi * 16 + hi * 4;
      const int n = n0 + WCOL + ni * 16 + lo;
      float v4[4];
#pragma unroll
      for (int reg = 0; reg < 4; reg++) {
        float v = acc[mi][ni][reg] + bias[n];
        if (FLAGS & 8) v += resid[(size_t)(mb + reg) * N + n];
        if (FLAGS & 1) v = fmaxf(v, 0.f);
        v4[reg] = v;
      }
      if (FLAGS & 4) {
        const int seg = n >> 10, nn = n & 1023;
        const int hh = nn >> 6, dd = nn & 63;
        const int bb = mb >> 11, ll = mb & 2047;
        u16* dst = (u16*)Cout + (size_t)seg * 4194304;
        if (seg == 0) {
#pragma unroll
          for (int reg = 0; reg < 4; reg++)
            dst[((size_t)(bb * 16 + hh) * LSEQ + ll + reg) * 64 + dd] = f2b(v4[reg] * QSCALE);
        } else if (seg == 1) {
#pragma unroll
          for (int reg = 0; reg < 4; reg++)
            dst[((size_t)(bb * 16 + hh) * LSEQ + ll + reg) * 64 + dd] = f2b(v4[reg]);
        } else {
          ushort4 o;
          o.x = f2b(v4[0]); o.y = f2b(v4[1]); o.z = f2b(v4[2]); o.w = f2b(v4[3]);
          *(ushort4*)&((u16*)dst)[((size_t)(bb * 16 + hh) * 64 + dd) * LSEQ + ll] = o;
        }
      } else if (FLAGS & 2) {
        u16* dst = (u16*)Cout;
#pragma unroll
        for (int reg = 0; reg < 4; reg++) dst[(size_t)(mb + reg) * N + n] = f2b(v4[reg]);
      } else {
        float* dst = (float*)Cout;
#pragma unroll
        for (int reg = 0; reg < 4; reg++) dst[(size_t)(mb + reg) * N + n] = v4[reg];
      }
    }
}

// ------------- fused rel-pos flash attention: transposed dataflow + LDS staging -------------
// Qh/Kh = [B*H, L, 64] bf16; Vt = [B*H, 64, L] bf16; Ob = [B*L, 1024] bf16.
// S^T = mfma(K,Q): each lane owns one query row (col=lo) -> in-lane softmax (4 shfls/tile),
// P stays in registers (B-operand, k-slot permutation matched by V A-frags from LDS).
// K/V^T staged in LDS via global_load_lds (shared by 4 waves), double-buffered, 1 barrier/tile.
__global__ __launch_bounds__(256) void k_attn(const u16* __restrict__ Qh, const u16* __restrict__ Kh,
                                              const u16* __restrict__ Vt, const u16* __restrict__ Eb,
                                              u16* __restrict__ Ob) {
  __shared__ __align__(16) u16 Ksh[2][64 * 64];   // [j][dh], row-XOR swizzled
  __shared__ __align__(16) u16 Vts[2][64 * 64];   // [dh][j], row-XOR swizzled
  __shared__ __align__(16) float Gsh[4][16 * 82]; // per-wave skew buffer [lo][82]

  const int tid = threadIdx.x;
  const int lane = tid & 63, wave = tid >> 6;
  const int lo = lane & 15, hi = lane >> 4;

  // XCD-chunked mapping: XCD c owns heads [4c, 4c+4)
  const int hb = blockIdx.x;
  const int logical = (hb & 7) * 128 + (hb >> 3);
  const int bh = logical >> 5;
  const int l0 = (logical & 31) * 64;
  const int bb = bh >> 4, hh = bh & 15;
  const int lw = l0 + wave * 16;

  const u16* Qb = Qh + (size_t)bh * LSEQ * 64;
  const char* Kb = (const char*)(Kh + (size_t)bh * LSEQ * 64);
  const char* Vb = (const char*)(Vt + (size_t)bh * 64 * LSEQ);

  const int colsw = ((lane & 7) * 16) ^ (((lane >> 3) & 7) << 4);  // staging src col
  const int swzv = (lo & 7) << 4;                                  // read-side row swizzle
  const int c0 = (hi * 16) ^ swzv;

  auto stageKV = [&](int buf_, int j0_) {
#pragma unroll
    for (int i = 0; i < 2; i++) {
      char* kd = (char*)&Ksh[buf_][0] + wave * 2048 + i * 1024;
      const char* ks = Kb + (size_t)(j0_ + wave * 16 + i * 8 + (lane >> 3)) * 128 + colsw;
      g2l16(ks, kd);
      char* vd = (char*)&Vts[buf_][0] + wave * 2048 + i * 1024;
      const char* vs = Vb + (size_t)(wave * 16 + i * 8 + (lane >> 3)) * (LSEQ * 2) + (size_t)j0_ * 2 + colsw;
      g2l16(vs, vd);
    }
  };

  // Q as B-operand: col=lo -> query lw+lo, k = 32*half + hi*8 + e
  s16x8 aq[2];
  aq[0] = *(const s16x8*)(Qb + (size_t)(lw + lo) * 64 + hi * 8);
  aq[1] = *(const s16x8*)(Qb + (size_t)(lw + lo) * 64 + 32 + hi * 8);

  float m_run = -1e30f, l_run = 0.f;
  f32x4 oacc[4];
#pragma unroll
  for (int f = 0; f < 4; f++) oacc[f] = (f32x4){0.f, 0.f, 0.f, 0.f};

  float* gw = &Gsh[wave][0];

  stageKV(0, 0);
  int buf = 0;

  for (int t = 0; t < 32; t++) {
    const int j0 = t * 64;
    const bool has_rel = (j0 <= l0);
    __syncthreads();                        // staged buf ready
    if (t < 31) stageKV(buf ^ 1, j0 + 64);  // prefetch next (lands at next barrier)

    // E A-frags: global->reg (L1/L2-hot band; OOB rows read allocated ws, masked later)
    s16x8 e0[5], e1[5];
    if (has_rel) {
      const int waveBase = 2032 - lw + j0;
#pragma unroll
      for (int c2 = 0; c2 < 5; c2++) {
        const u16* ep = Eb + (size_t)(waveBase + c2 * 16 + lo) * 64;
        e0[c2] = *(const s16x8*)(ep + hi * 8);
        e1[c2] = *(const s16x8*)(ep + 32 + hi * 8);
      }
    }

    // V A-frags from LDS, permuted k-slots (issued early to hide ds latency)
    s16x4 vA[4][2], vB2[4][2];
#pragma unroll
    for (int f = 0; f < 4; f++) {
      const char* vrow = (const char*)&Vts[buf][0] + (f * 16 + lo) * 128;
#pragma unroll
      for (int m = 0; m < 2; m++) {
        vA[f][m]  = *(const s16x4*)(vrow + ((64 * m + 8 * hi) ^ swzv));
        vB2[f][m] = *(const s16x4*)(vrow + ((64 * m + 8 * hi + 32) ^ swzv));
      }
    }

    // S^T = mfma(K, Q): s4[c][reg] = S[jr = c*16+4hi+reg][q = lo]
    f32x4 s4[4];
#pragma unroll
    for (int c = 0; c < 4; c++) {
      const char* krow = (const char*)&Ksh[buf][0] + (c * 16 + lo) * 128;
      s16x8 a0 = *(const s16x8*)(krow + c0);
      s16x8 a1 = *(const s16x8*)(krow + (c0 ^ 64));
      s4[c] = (f32x4){0.f, 0.f, 0.f, 0.f};
      s4[c] = MFMA16(a0, aq[0], s4[c]);
      s4[c] = MFMA16(a1, aq[1], s4[c]);
    }

    // rel: G^T = mfma(E, Q), skew-gather through per-wave LDS (no barrier)
    if (has_rel) {
#pragma unroll
      for (int c2 = 0; c2 < 5; c2++) {
        f32x4 g = (f32x4){0.f, 0.f, 0.f, 0.f};
        g = MFMA16(e0[c2], aq[0], g);
        g = MFMA16(e1[c2], aq[1], g);
        *(f32x4*)(gw + 82 * lo + c2 * 16 + 4 * hi) = g;  // ds_write_b128
      }
      if (j0 < l0) {  // fully below diagonal
#pragma unroll
        for (int c = 0; c < 4; c++)
#pragma unroll
          for (int reg = 0; reg < 4; reg++)
            s4[c][reg] += gw[81 * lo + 15 + c * 16 + 4 * hi + reg];
      } else {        // diagonal tile: jr <= 16*wave + lo
        const int rmax = 16 * wave + lo;
#pragma unroll
        for (int c = 0; c < 4; c++)
#pragma unroll
          for (int reg = 0; reg < 4; reg++) {
            int jr = c * 16 + 4 * hi + reg;
            float g = gw[81 * lo + 15 + jr];
            s4[c][reg] += (jr <= rmax) ? g : 0.f;
          }
      }
    }

    // in-lane softmax (base-2)
    float mt = s4[0][0];
#pragma unroll
    for (int c = 0; c < 4; c++)
#pragma unroll
      for (int reg = 0; reg < 4; reg++) mt = fmaxf(mt, s4[c][reg]);
    mt = fmaxf(mt, __shfl_xor(mt, 16, 64));
    mt = fmaxf(mt, __shfl_xor(mt, 32, 64));
    float mnew = fmaxf(m_run, mt);
    float scl = exp2f(m_run - mnew);
    m_run = mnew;

    float p[4][4];
    float psum = 0.f;
#pragma unroll
    for (int c = 0; c < 4; c++)
#pragma unroll
      for (int reg = 0; reg < 4; reg++) {
        float pv = exp2f(s4[c][reg] - mnew);
        p[c][reg] = pv;
        psum += pv;
      }

#pragma unroll
    for (int f = 0; f < 4; f++)
#pragma unroll
      for (int reg = 0; reg < 4; reg++) oacc[f][reg] *= scl;

    // pack P into B-frags matching the k-slot permutation
    union UU { uint4 u; s16x8 v; };
    UU pb0, pb1;
    pb0.u = make_uint4(pk2(p[0][0], p[0][1]), pk2(p[0][2], p[0][3]),
                       pk2(p[1][0], p[1][1]), pk2(p[1][2], p[1][3]));
    pb1.u = make_uint4(pk2(p[2][0], p[2][1]), pk2(p[2][2], p[2][3]),
                       pk2(p[3][0], p[3][1]), pk2(p[3][2], p[3][3]));

    // O^T += V^T · P
#pragma unroll
    for (int f = 0; f < 4; f++) {
      s16x8 v0 = __builtin_shufflevector(vA[f][0], vB2[f][0], 0, 1, 2, 3, 4, 5, 6, 7);
      s16x8 v1 = __builtin_shufflevector(vA[f][1], vB2[f][1], 0, 1, 2, 3, 4, 5, 6, 7);
      oacc[f] = MFMA16(v0, pb0.v, oacc[f]);
      oacc[f] = MFMA16(v1, pb1.v, oacc[f]);
    }

    // psum cross-lane reduce (overlaps PV)
    psum += __shfl_xor(psum, 16, 64);
    psum += __shfl_xor(psum, 32, 64);
    l_run = l_run * scl + psum;

    buf ^= 1;
  }

  const float inv = 1.f / l_run;
  const size_t orow = (size_t)(bb * LSEQ + lw + lo) * 1024 + hh * 64;
#pragma unroll
  for (int f = 0; f < 4; f++) {
    ushort4 o;
    o.x = f2b(oacc[f][0] * inv); o.y = f2b(oacc[f][1] * inv);
    o.z = f2b(oacc[f][2] * inv); o.w = f2b(oacc[f][3] * inv);
    *(ushort4*)(Ob + orow + f * 16 + 4 * hi) = o;
  }
}

// ------------- LayerNorm over rows of 1024, optional bf16 copy -------------
__global__ __launch_bounds__(256) void k_layernorm(const float* __restrict__ X, const float* __restrict__ gw,
                                                   const float* __restrict__ bw, float* __restrict__ outF,
                                                   u16* __restrict__ outB) {
  __shared__ float red[2][4];
  const int row = blockIdx.x, tid = threadIdx.x;
  const int lane = tid & 63, wave = tid >> 6;
  const float* x = X + (size_t)row * 1024;
  float4 v = *(const float4*)(x + tid * 4);
  float s = v.x + v.y + v.z + v.w;
  float s2 = v.x * v.x + v.y * v.y + v.z * v.z + v.w * v.w;
#pragma unroll
  for (int msk = 1; msk <= 32; msk <<= 1) {
    s += __shfl_xor(s, msk, 64);
    s2 += __shfl_xor(s2, msk, 64);
  }
  if (lane == 0) { red[0][wave] = s; red[1][wave] = s2; }
  __syncthreads();
  s = red[0][0] + red[0][1] + red[0][2] + red[0][3];
  s2 = red[1][0] + red[1][1] + red[1][2] + red[1][3];
  float mean = s * (1.f / 1024.f);
  float var = s2 * (1.f / 1024.f) - mean * mean;
  float rs = rsqrtf(var + 1e-6f);
  float4 g4 = *(const float4*)(gw + tid * 4);
  float4 b4 = *(const float4*)(bw + tid * 4);
  float4 o;
  o.x = (v.x - mean) * rs * g4.x + b4.x;
  o.y = (v.y - mean) * rs * g4.y + b4.y;
  o.z = (v.z - mean) * rs * g4.z + b4.z;
  o.w = (v.w - mean) * rs * g4.w + b4.w;
  *(float4*)(outF + (size_t)row * 1024 + tid * 4) = o;
  if (outB) {
    ushort4 ob;
    ob.x = f2b(o.x); ob.y = f2b(o.y); ob.z = f2b(o.z); ob.w = f2b(o.w);
    *(ushort4*)(outB + (size_t)row * 1024 + tid * 4) = ob;
  }
}

extern "C" void kernel_launch(void* const* d_in, const int* in_sizes, int n_in,
                              void* d_out, int out_size, void* d_ws, size_t ws_size,
                              hipStream_t stream) {
  const float* x   = (const float*)d_in[0];
  const float* Wq  = (const float*)d_in[1];
  const float* bq  = (const float*)d_in[2];
  const float* Wk  = (const float*)d_in[3];
  const float* bk  = (const float*)d_in[4];
  const float* Wv  = (const float*)d_in[5];
  const float* bv  = (const float*)d_in[6];
  const float* Wo  = (const float*)d_in[7];
  const float* bo  = (const float*)d_in[8];
  const float* E   = (const float*)d_in[9];
  const float* W1  = (const float*)d_in[10];
  const float* b1  = (const float*)d_in[11];
  const float* W2  = (const float*)d_in[12];
  const float* b2  = (const float*)d_in[13];
  const float* g1  = (const float*)d_in[14];
  const float* be1 = (const float*)d_in[15];
  const float* g2  = (const float*)d_in[16];
  const float* be2 = (const float*)d_in[17];

  char* ws = (char*)d_ws;
  const size_t MB = 1ull << 20;
  u16* Wqt = (u16*)(ws + 0 * MB);          // 6MB contiguous [3072][1024] (Wq/Wk/Wv)
  u16* Wkt = (u16*)(ws + 2 * MB);
  u16* Wvt = (u16*)(ws + 4 * MB);
  u16* Wot = (u16*)(ws + 6 * MB);          // 2MB
  u16* W1t = (u16*)(ws + 8 * MB);          // 8MB [4096][1024]
  u16* W2t = (u16*)(ws + 16 * MB);         // 8MB [1024][4096]
  u16* Ebf = (u16*)(ws + 24 * MB);         // 256KB [2048][64]
  float* bcat = (float*)(ws + 24 * MB + 512 * 1024);  // 12KB (gap tolerates E-band overrun)
  u16* xb  = (u16*)(ws + 25 * MB);         // 8MB [4096][1024]
  u16* qb  = (u16*)(ws + 33 * MB);         // 8MB head-major (QSCALE'd)
  u16* kb  = (u16*)(ws + 41 * MB);         // 8MB head-major
  u16* vt  = (u16*)(ws + 49 * MB);         // 8MB transposed [bh][64][L]
  u16* ao  = (u16*)(ws + 57 * MB);         // 8MB [4096][1024]
  float* t1 = (float*)(ws + 65 * MB);      // 16MB f32
  u16* o1b  = (u16*)(ws + 25 * MB);        // reuse xb
  float* o1f = (float*)(ws + 33 * MB);     // reuse qb/kb
  u16* h1b  = (u16*)(ws + 49 * MB);        // reuse vt/ao/t1, 32MB [4096][4096]
  float* outF = (float*)d_out;

  // 1) conversions / prep
  k_cvt<<<4096, 256, 0, stream>>>(x, xb, 4096 * 1024);
  k_cvt<<<128, 256, 0, stream>>>(E, Ebf, 2048 * 64);
  k_prep<<<12, 256, 0, stream>>>(bq, bk, bv, bcat);
  k_transpose<<<dim3(16, 16), 256, 0, stream>>>(Wq, Wqt, 1024, 1024);
  k_transpose<<<dim3(16, 16), 256, 0, stream>>>(Wk, Wkt, 1024, 1024);
  k_transpose<<<dim3(16, 16), 256, 0, stream>>>(Wv, Wvt, 1024, 1024);
  k_transpose<<<dim3(16, 16), 256, 0, stream>>>(Wo, Wot, 1024, 1024);
  k_transpose<<<dim3(64, 16), 256, 0, stream>>>(W1, W1t, 1024, 4096);
  k_transpose<<<dim3(16, 64), 256, 0, stream>>>(W2, W2t, 4096, 1024);

  // 2) fused QKV projection (writes qb, kb, vt)
  k_gemm<128, 4><<<dim3(24, 32), 256, 0, stream>>>(xb, Wqt, bcat, nullptr, qb, 4096, 3072, 1024);

  // 3) rel-pos flash attention -> ao
  k_attn<<<dim3(1024), 256, 0, stream>>>(qb, kb, vt, Ebf, ao);

  // 4) O-proj + residual(x) -> t1 f32
  k_gemm<64, 8><<<dim3(16, 32), 256, 0, stream>>>(ao, Wot, bo, x, t1, 4096, 1024, 1024);

  // 5) LN1 -> o1f (f32) + o1b (bf16)
  k_layernorm<<<4096, 256, 0, stream>>>(t1, g1, be1, o1f, o1b);

  // 6) FFN1: relu(out1 @ W1 + b1) -> h1b bf16
  k_gemm<128, 3><<<dim3(32, 32), 256, 0, stream>>>(o1b, W1t, b1, nullptr, h1b, 4096, 4096, 1024);

  // 7) FFN2 + residual(o1f) -> d_out f32
  k_gemm<64, 8><<<dim3(16, 32), 256, 0, stream>>>(h1b, W2t, b2, o1f, outF, 4096, 1024, 4096);

  // 8) LN2 in-place on d_out
  k_layernorm<<<4096, 256, 0, stream>>>(outF, g2, be2, outF, nullptr);
}

// Round 6
// 362.470 us; speedup vs baseline: 1.9197x; 1.4959x over previous
//
#include <hip/hip_runtime.h>

typedef unsigned short u16;
typedef __attribute__((ext_vector_type(4))) short s16x4;
typedef __attribute__((ext_vector_type(8))) short s16x8;
typedef __attribute__((ext_vector_type(4))) float f32x4;

#define MFMA16(a,b,c) __builtin_amdgcn_mfma_f32_16x16x32_bf16((a),(b),(c),0,0,0)
#define LSEQ 2048
#define QSCALE 0.18033688011112042f  /* 0.125 * log2(e) */

__device__ __forceinline__ u16 f2b(float f) {
  union { float f; unsigned u; } v; v.f = f;
  unsigned r = v.u + 0x7FFFu + ((v.u >> 16) & 1u);
  return (u16)(r >> 16);
}
__device__ __forceinline__ u16 f2b_fast(float f) {
  union { float f; unsigned u; } v; v.f = f;
  return (u16)((v.u + 0x8000u) >> 16);
}
__device__ __forceinline__ unsigned pk2(float a, float b) {
  return (unsigned)f2b_fast(a) | ((unsigned)f2b_fast(b) << 16);
}
__device__ __forceinline__ void g2l16(const void* g, void* l) {
  __builtin_amdgcn_global_load_lds(
      (const __attribute__((address_space(1))) unsigned int*)g,
      (__attribute__((address_space(3))) unsigned int*)l, 16, 0, 0);
}

// ---------------- convert f32 -> bf16, 4 elems/thread ----------------
__global__ __launch_bounds__(256) void k_cvt(const float* __restrict__ in, u16* __restrict__ out, int n) {
  int i = (blockIdx.x * 256 + threadIdx.x) * 4;
  if (i + 3 < n) {
    float4 v = *(const float4*)(in + i);
    ushort4 o;
    o.x = f2b(v.x); o.y = f2b(v.y); o.z = f2b(v.z); o.w = f2b(v.w);
    *(ushort4*)(out + i) = o;
  }
}

// ---------------- bias concat ----------------
__global__ __launch_bounds__(256) void k_prep(const float* __restrict__ bq, const float* __restrict__ bk,
                                              const float* __restrict__ bv, float* __restrict__ bcat) {
  int i = blockIdx.x * 256 + threadIdx.x;
  if (i < 1024) bcat[i] = bq[i];
  else if (i < 2048) bcat[i] = bk[i - 1024];
  else if (i < 3072) bcat[i] = bv[i - 2048];
}

// ------------- transpose+convert: W[K,N] f32 -> Wt[N,K] bf16 -------------
__global__ __launch_bounds__(256) void k_transpose(const float* __restrict__ W, u16* __restrict__ Wt, int K, int N) {
  __shared__ float T[64][65];
  int k0 = blockIdx.y * 64, n0 = blockIdx.x * 64;
  int r = threadIdx.x >> 4;
  int c4 = (threadIdx.x & 15) * 4;
#pragma unroll
  for (int i = 0; i < 4; i++) {
    float4 v = *(const float4*)(W + (size_t)(k0 + r + i * 16) * N + n0 + c4);
    T[r + i * 16][c4 + 0] = v.x; T[r + i * 16][c4 + 1] = v.y;
    T[r + i * 16][c4 + 2] = v.z; T[r + i * 16][c4 + 3] = v.w;
  }
  __syncthreads();
#pragma unroll
  for (int i = 0; i < 4; i++) {
    int nl = r + i * 16;
    ushort4 o;
    o.x = f2b(T[c4 + 0][nl]); o.y = f2b(T[c4 + 1][nl]);
    o.z = f2b(T[c4 + 2][nl]); o.w = f2b(T[c4 + 3][nl]);
    *(ushort4*)(Wt + (size_t)(n0 + nl) * K + k0 + c4) = o;
  }
}

// ------------- bf16 MFMA GEMM, gload_lds dbuf, swizzled LDS -------------
// C[M,N] = A[M,K] @ Bt[N,K]^T + bias.  FLAGS: 1=RELU, 2=BF16OUT, 4=QKV, 8=RESID(f32 out)
template <int BN, int FLAGS>
__global__ __launch_bounds__(256) void k_gemm(const u16* __restrict__ A, const u16* __restrict__ Bt,
                                              const float* __restrict__ bias, const float* __restrict__ resid,
                                              void* __restrict__ Cout, int M, int N, int K) {
  constexpr int MI = (BN == 128) ? 4 : 2;
  __shared__ __align__(16) u16 As[2][128 * 32];
  __shared__ __align__(16) u16 Bs[2][BN * 32];
  const int tid = threadIdx.x;
  const int lane = tid & 63, wave = tid >> 6;
  const int lo = lane & 15, hi = lane >> 4;
  const int WROW = (BN == 128) ? (wave >> 1) * 64 : wave * 32;
  const int WCOL = (BN == 128) ? (wave & 1) * 64 : 0;
  const int m0 = blockIdx.y * 128, n0 = blockIdx.x * BN;

  const int colg = ((lane & 3) * 16) ^ (((lane >> 3) & 3) << 4);
  const int arow = wave * 32 + (lane >> 2);
  const int swzr = ((lane >> 1) & 3) << 4;

  f32x4 acc[MI][4];
#pragma unroll
  for (int mi = 0; mi < MI; mi++)
#pragma unroll
    for (int ni = 0; ni < 4; ni++) acc[mi][ni] = (f32x4){0.f, 0.f, 0.f, 0.f};

  const char* Ab = (const char*)A;
  const char* Bb = (const char*)Bt;
  const int nt = K >> 5;

  auto stage = [&](int buf, int t) {
    const int k0 = t * 32;
    char* ad = (char*)&As[buf][0] + wave * 2048;
    const char* as = Ab + ((size_t)(m0 + arow) * K + k0) * 2 + colg;
    g2l16(as, ad);
    g2l16(as + (size_t)16 * K * 2, ad + 1024);
    if (BN == 128) {
      char* bd = (char*)&Bs[buf][0] + wave * 2048;
      const char* bs = Bb + ((size_t)(n0 + arow) * K + k0) * 2 + colg;
      g2l16(bs, bd);
      g2l16(bs + (size_t)16 * K * 2, bd + 1024);
    } else {
      char* bd = (char*)&Bs[buf][0] + wave * 1024;
      const int brow = wave * 16 + (lane >> 2);
      const char* bs = Bb + ((size_t)(n0 + brow) * K + k0) * 2 + colg;
      g2l16(bs, bd);
    }
  };

  stage(0, 0);
  int buf = 0;
  for (int t = 0; t < nt; t++) {
    __syncthreads();
    if (t + 1 < nt) stage(buf ^ 1, t + 1);
    const char* ab = (const char*)&As[buf][0];
    const char* bb2 = (const char*)&Bs[buf][0];
    s16x8 af[MI], bfr[4];
#pragma unroll
    for (int mi = 0; mi < MI; mi++) {
      int row = WROW + mi * 16 + lo;
      af[mi] = *(const s16x8*)(ab + row * 64 + ((hi * 16) ^ swzr));
    }
#pragma unroll
    for (int ni = 0; ni < 4; ni++) {
      int row = WCOL + ni * 16 + lo;
      bfr[ni] = *(const s16x8*)(bb2 + row * 64 + ((hi * 16) ^ swzr));
    }
#pragma unroll
    for (int mi = 0; mi < MI; mi++)
#pragma unroll
      for (int ni = 0; ni < 4; ni++)
        acc[mi][ni] = MFMA16(af[mi], bfr[ni], acc[mi][ni]);
    buf ^= 1;
  }

#pragma unroll
  for (int mi = 0; mi < MI; mi++)
#pragma unroll
    for (int ni = 0; ni < 4; ni++) {
      const int mb = m0 + WROW + mi * 16 + hi * 4;
      const int n = n0 + WCOL + ni * 16 + lo;
      float v4[4];
#pragma unroll
      for (int reg = 0; reg < 4; reg++) {
        float v = acc[mi][ni][reg] + bias[n];
        if (FLAGS & 8) v += resid[(size_t)(mb + reg) * N + n];
        if (FLAGS & 1) v = fmaxf(v, 0.f);
        v4[reg] = v;
      }
      if (FLAGS & 4) {
        const int seg = n >> 10, nn = n & 1023;
        const int hh = nn >> 6, dd = nn & 63;
        const int bb = mb >> 11, ll = mb & 2047;
        u16* dst = (u16*)Cout + (size_t)seg * 4194304;
        if (seg == 0) {
#pragma unroll
          for (int reg = 0; reg < 4; reg++)
            dst[((size_t)(bb * 16 + hh) * LSEQ + ll + reg) * 64 + dd] = f2b(v4[reg] * QSCALE);
        } else if (seg == 1) {
#pragma unroll
          for (int reg = 0; reg < 4; reg++)
            dst[((size_t)(bb * 16 + hh) * LSEQ + ll + reg) * 64 + dd] = f2b(v4[reg]);
        } else {
          ushort4 o;
          o.x = f2b(v4[0]); o.y = f2b(v4[1]); o.z = f2b(v4[2]); o.w = f2b(v4[3]);
          *(ushort4*)&((u16*)dst)[((size_t)(bb * 16 + hh) * 64 + dd) * LSEQ + ll] = o;
        }
      } else if (FLAGS & 2) {
        u16* dst = (u16*)Cout;
#pragma unroll
        for (int reg = 0; reg < 4; reg++) dst[(size_t)(mb + reg) * N + n] = f2b(v4[reg]);
      } else {
        float* dst = (float*)Cout;
#pragma unroll
        for (int reg = 0; reg < 4; reg++) dst[(size_t)(mb + reg) * N + n] = v4[reg];
      }
    }
}

// ------------- fused rel-pos flash attention: transposed dataflow, 8 waves/block -------------
// Qh/Kh = [B*H, L, 64] bf16; Vt = [B*H, 64, L] bf16; Ob = [B*L, 1024] bf16.
// 512-thread blocks, 128 query rows (16/wave). S^T = mfma(K,Q): lane owns one query row,
// in-lane softmax, in-register P (k-slot permutation matched by V A-frags from LDS).
// K/V^T staged once per tile via global_load_lds, shared by 8 waves, dbuf, 1 barrier/tile.
__global__ __launch_bounds__(512, 4) void k_attn(const u16* __restrict__ Qh, const u16* __restrict__ Kh,
                                                 const u16* __restrict__ Vt, const u16* __restrict__ Eb,
                                                 u16* __restrict__ Ob) {
  __shared__ __align__(16) u16 Ksh[2][64 * 64];   // [j][dh], row-XOR swizzled
  __shared__ __align__(16) u16 Vts[2][64 * 64];   // [dh][j], row-XOR swizzled
  __shared__ __align__(16) float Gsh[8][16 * 84]; // per-wave skew buffer, write stride 84

  const int tid = threadIdx.x;
  const int lane = tid & 63, wave = tid >> 6;
  const int lo = lane & 15, hi = lane >> 4;

  // XCD-chunked mapping + load-balance flip (co-resident pairs sum to equal rel work)
  const int hb = blockIdx.x;
  const int x = hb & 7;
  const int kk = hb >> 3;                       // 0..63 within XCD
  const int bh = x * 4 + (kk >> 4);
  const int ti = (kk & 32) ? (15 - (kk & 15)) : (kk & 15);
  const int l0 = ti * 128;
  const int bb = bh >> 4, hh = bh & 15;
  const int lw = l0 + wave * 16;

  const u16* Qb = Qh + (size_t)bh * LSEQ * 64;
  const char* Kb = (const char*)(Kh + (size_t)bh * LSEQ * 64);
  const char* Vb = (const char*)(Vt + (size_t)bh * 64 * LSEQ);

  const int colsw = ((lane & 7) * 16) ^ (((lane >> 3) & 7) << 4);  // staging src col
  const int swzv = (lo & 7) << 4;                                  // read-side row swizzle
  const int c0 = (hi * 16) ^ swzv;

  auto stageKV = [&](int buf_, int j0_) {
    char* kd = (char*)&Ksh[buf_][0] + wave * 1024;
    const char* ks = Kb + (size_t)(j0_ + wave * 8 + (lane >> 3)) * 128 + colsw;
    g2l16(ks, kd);
    char* vd = (char*)&Vts[buf_][0] + wave * 1024;
    const char* vs = Vb + (size_t)(wave * 8 + (lane >> 3)) * (LSEQ * 2) + (size_t)j0_ * 2 + colsw;
    g2l16(vs, vd);
  };

  // Q as B-operand: col=lo -> query lw+lo, k = 32*half + hi*8 + e
  s16x8 aq[2];
  aq[0] = *(const s16x8*)(Qb + (size_t)(lw + lo) * 64 + hi * 8);
  aq[1] = *(const s16x8*)(Qb + (size_t)(lw + lo) * 64 + 32 + hi * 8);

  float m_run = -1e30f, l_run = 0.f;
  f32x4 oacc[4];
#pragma unroll
  for (int f = 0; f < 4; f++) oacc[f] = (f32x4){0.f, 0.f, 0.f, 0.f};

  float* gw = &Gsh[wave][0];

  stageKV(0, 0);
  int buf = 0;

  for (int t = 0; t < 32; t++) {
    const int j0 = t * 64;
    const bool has_rel = (j0 <= lw);
    __syncthreads();                        // staged buf ready
    if (t < 31) stageKV(buf ^ 1, j0 + 64);  // prefetch next (drained at next barrier)

    // S^T = mfma(K, Q): s4[c][reg] = S[jr = c*16+4hi+reg][q = lo]
    f32x4 s4[4];
#pragma unroll
    for (int c = 0; c < 4; c++) {
      const char* krow = (const char*)&Ksh[buf][0] + (c * 16 + lo) * 128;
      s16x8 a0 = *(const s16x8*)(krow + c0);
      s16x8 a1 = *(const s16x8*)(krow + (c0 ^ 64));
      s4[c] = (f32x4){0.f, 0.f, 0.f, 0.f};
      s4[c] = MFMA16(a0, aq[0], s4[c]);
      s4[c] = MFMA16(a1, aq[1], s4[c]);
    }

    // rel: G^T = mfma(E, Q), skew-gather through per-wave LDS (no barrier)
    if (has_rel) {
      const int waveBase = 2032 - lw + j0;
      const u16* erow = Qh;  // placeholder silence
      const u16* ep0 = Eb + (size_t)(waveBase + lo) * 64 + hi * 8;
      s16x8 ec0 = *(const s16x8*)(ep0);
      s16x8 ec1 = *(const s16x8*)(ep0 + 32);
#pragma unroll
      for (int c2 = 0; c2 < 5; c2++) {
        s16x8 en0, en1;
        if (c2 < 4) {
          const u16* epn = ep0 + (size_t)(c2 + 1) * 16 * 64;
          en0 = *(const s16x8*)(epn);
          en1 = *(const s16x8*)(epn + 32);
        }
        f32x4 g = (f32x4){0.f, 0.f, 0.f, 0.f};
        g = MFMA16(ec0, aq[0], g);
        g = MFMA16(ec1, aq[1], g);
        *(f32x4*)(gw + 84 * lo + c2 * 16 + 4 * hi) = g;  // aligned ds_write_b128
        if (c2 < 4) { ec0 = en0; ec1 = en1; }
      }
      const int dd = lw - j0;
      if (dd >= 64) {  // fully below diagonal
#pragma unroll
        for (int c = 0; c < 4; c++)
#pragma unroll
          for (int reg = 0; reg < 4; reg++)
            s4[c][reg] += gw[83 * lo + 15 + c * 16 + 4 * hi + reg];
      } else {         // diagonal tile: jr <= dd + lo
        const int rmax = dd + lo;
#pragma unroll
        for (int c = 0; c < 4; c++)
#pragma unroll
          for (int reg = 0; reg < 4; reg++) {
            int jr = c * 16 + 4 * hi + reg;
            float g = gw[83 * lo + 15 + jr];
            s4[c][reg] += (jr <= rmax) ? g : 0.f;
          }
      }
      (void)erow;
    }

    // V A-frags from LDS, permuted k-slots (issued here to lead PV while bounding liveness)
    s16x4 vA[4][2], vB2[4][2];
#pragma unroll
    for (int f = 0; f < 4; f++) {
      const char* vrow = (const char*)&Vts[buf][0] + (f * 16 + lo) * 128;
#pragma unroll
      for (int m = 0; m < 2; m++) {
        vA[f][m]  = *(const s16x4*)(vrow + ((64 * m + 8 * hi) ^ swzv));
        vB2[f][m] = *(const s16x4*)(vrow + ((64 * m + 8 * hi + 32) ^ swzv));
      }
    }

    // in-lane softmax (base-2)
    float mt = s4[0][0];
#pragma unroll
    for (int c = 0; c < 4; c++)
#pragma unroll
      for (int reg = 0; reg < 4; reg++) mt = fmaxf(mt, s4[c][reg]);
    mt = fmaxf(mt, __shfl_xor(mt, 16, 64));
    mt = fmaxf(mt, __shfl_xor(mt, 32, 64));
    float mnew = fmaxf(m_run, mt);
    float scl = exp2f(m_run - mnew);
    m_run = mnew;

    unsigned w8[8];
    float psum = 0.f;
#pragma unroll
    for (int c = 0; c < 4; c++) {
      float a0 = exp2f(s4[c][0] - mnew), a1 = exp2f(s4[c][1] - mnew);
      float a2 = exp2f(s4[c][2] - mnew), a3 = exp2f(s4[c][3] - mnew);
      psum += (a0 + a1) + (a2 + a3);
      w8[c * 2] = pk2(a0, a1);
      w8[c * 2 + 1] = pk2(a2, a3);
    }

#pragma unroll
    for (int f = 0; f < 4; f++)
#pragma unroll
      for (int reg = 0; reg < 4; reg++) oacc[f][reg] *= scl;

    union UU { uint4 u; s16x8 v; };
    UU pb0, pb1;
    pb0.u = make_uint4(w8[0], w8[1], w8[2], w8[3]);
    pb1.u = make_uint4(w8[4], w8[5], w8[6], w8[7]);

    // O^T += V^T · P
#pragma unroll
    for (int f = 0; f < 4; f++) {
      s16x8 v0 = __builtin_shufflevector(vA[f][0], vB2[f][0], 0, 1, 2, 3, 4, 5, 6, 7);
      s16x8 v1 = __builtin_shufflevector(vA[f][1], vB2[f][1], 0, 1, 2, 3, 4, 5, 6, 7);
      oacc[f] = MFMA16(v0, pb0.v, oacc[f]);
      oacc[f] = MFMA16(v1, pb1.v, oacc[f]);
    }

    // psum cross-lane reduce (overlaps PV)
    psum += __shfl_xor(psum, 16, 64);
    psum += __shfl_xor(psum, 32, 64);
    l_run = l_run * scl + psum;

    buf ^= 1;
  }

  const float inv = 1.f / l_run;
  const size_t orow = (size_t)(bb * LSEQ + lw + lo) * 1024 + hh * 64;
#pragma unroll
  for (int f = 0; f < 4; f++) {
    ushort4 o;
    o.x = f2b(oacc[f][0] * inv); o.y = f2b(oacc[f][1] * inv);
    o.z = f2b(oacc[f][2] * inv); o.w = f2b(oacc[f][3] * inv);
    *(ushort4*)(Ob + orow + f * 16 + 4 * hi) = o;
  }
}

// ------------- LayerNorm over rows of 1024, optional bf16 copy -------------
__global__ __launch_bounds__(256) void k_layernorm(const float* __restrict__ X, const float* __restrict__ gw,
                                                   const float* __restrict__ bw, float* __restrict__ outF,
                                                   u16* __restrict__ outB) {
  __shared__ float red[2][4];
  const int row = blockIdx.x, tid = threadIdx.x;
  const int lane = tid & 63, wave = tid >> 6;
  const float* x = X + (size_t)row * 1024;
  float4 v = *(const float4*)(x + tid * 4);
  float s = v.x + v.y + v.z + v.w;
  float s2 = v.x * v.x + v.y * v.y + v.z * v.z + v.w * v.w;
#pragma unroll
  for (int msk = 1; msk <= 32; msk <<= 1) {
    s += __shfl_xor(s, msk, 64);
    s2 += __shfl_xor(s2, msk, 64);
  }
  if (lane == 0) { red[0][wave] = s; red[1][wave] = s2; }
  __syncthreads();
  s = red[0][0] + red[0][1] + red[0][2] + red[0][3];
  s2 = red[1][0] + red[1][1] + red[1][2] + red[1][3];
  float mean = s * (1.f / 1024.f);
  float var = s2 * (1.f / 1024.f) - mean * mean;
  float rs = rsqrtf(var + 1e-6f);
  float4 g4 = *(const float4*)(gw + tid * 4);
  float4 b4 = *(const float4*)(bw + tid * 4);
  float4 o;
  o.x = (v.x - mean) * rs * g4.x + b4.x;
  o.y = (v.y - mean) * rs * g4.y + b4.y;
  o.z = (v.z - mean) * rs * g4.z + b4.z;
  o.w = (v.w - mean) * rs * g4.w + b4.w;
  *(float4*)(outF + (size_t)row * 1024 + tid * 4) = o;
  if (outB) {
    ushort4 ob;
    ob.x = f2b(o.x); ob.y = f2b(o.y); ob.z = f2b(o.z); ob.w = f2b(o.w);
    *(ushort4*)(outB + (size_t)row * 1024 + tid * 4) = ob;
  }
}

extern "C" void kernel_launch(void* const* d_in, const int* in_sizes, int n_in,
                              void* d_out, int out_size, void* d_ws, size_t ws_size,
                              hipStream_t stream) {
  const float* x   = (const float*)d_in[0];
  const float* Wq  = (const float*)d_in[1];
  const float* bq  = (const float*)d_in[2];
  const float* Wk  = (const float*)d_in[3];
  const float* bk  = (const float*)d_in[4];
  const float* Wv  = (const float*)d_in[5];
  const float* bv  = (const float*)d_in[6];
  const float* Wo  = (const float*)d_in[7];
  const float* bo  = (const float*)d_in[8];
  const float* E   = (const float*)d_in[9];
  const float* W1  = (const float*)d_in[10];
  const float* b1  = (const float*)d_in[11];
  const float* W2  = (const float*)d_in[12];
  const float* b2  = (const float*)d_in[13];
  const float* g1  = (const float*)d_in[14];
  const float* be1 = (const float*)d_in[15];
  const float* g2  = (const float*)d_in[16];
  const float* be2 = (const float*)d_in[17];

  char* ws = (char*)d_ws;
  const size_t MB = 1ull << 20;
  u16* Wqt = (u16*)(ws + 0 * MB);          // 6MB contiguous [3072][1024] (Wq/Wk/Wv)
  u16* Wot = (u16*)(ws + 6 * MB);          // 2MB
  u16* W1t = (u16*)(ws + 8 * MB);          // 8MB [4096][1024]
  u16* W2t = (u16*)(ws + 16 * MB);         // 8MB [1024][4096]
  u16* Ebf = (u16*)(ws + 24 * MB);         // 256KB [2048][64] (+ slack for OOB band reads)
  float* bcat = (float*)(ws + 24 * MB + 512 * 1024);  // 12KB
  u16* xb  = (u16*)(ws + 25 * MB);         // 8MB [4096][1024]
  u16* qb  = (u16*)(ws + 33 * MB);         // 8MB head-major (QSCALE'd)
  u16* kb  = (u16*)(ws + 41 * MB);         // 8MB head-major
  u16* vt  = (u16*)(ws + 49 * MB);         // 8MB transposed [bh][64][L]
  u16* ao  = (u16*)(ws + 57 * MB);         // 8MB [4096][1024]
  float* t1 = (float*)(ws + 65 * MB);      // 16MB f32
  u16* o1b  = (u16*)(ws + 25 * MB);        // reuse xb
  float* o1f = (float*)(ws + 33 * MB);     // reuse qb/kb
  u16* h1b  = (u16*)(ws + 49 * MB);        // reuse vt/ao/t1, 32MB [4096][4096]
  float* outF = (float*)d_out;

  u16* Wkt = Wqt + 1024 * 1024;
  u16* Wvt = Wqt + 2 * 1024 * 1024;

  // 1) conversions / prep
  k_cvt<<<4096, 256, 0, stream>>>(x, xb, 4096 * 1024);
  k_cvt<<<128, 256, 0, stream>>>(E, Ebf, 2048 * 64);
  k_prep<<<12, 256, 0, stream>>>(bq, bk, bv, bcat);
  k_transpose<<<dim3(16, 16), 256, 0, stream>>>(Wq, Wqt, 1024, 1024);
  k_transpose<<<dim3(16, 16), 256, 0, stream>>>(Wk, Wkt, 1024, 1024);
  k_transpose<<<dim3(16, 16), 256, 0, stream>>>(Wv, Wvt, 1024, 1024);
  k_transpose<<<dim3(16, 16), 256, 0, stream>>>(Wo, Wot, 1024, 1024);
  k_transpose<<<dim3(64, 16), 256, 0, stream>>>(W1, W1t, 1024, 4096);
  k_transpose<<<dim3(16, 64), 256, 0, stream>>>(W2, W2t, 4096, 1024);

  // 2) fused QKV projection (writes qb, kb, vt)
  k_gemm<128, 4><<<dim3(24, 32), 256, 0, stream>>>(xb, Wqt, bcat, nullptr, qb, 4096, 3072, 1024);

  // 3) rel-pos flash attention -> ao
  k_attn<<<dim3(512), 512, 0, stream>>>(qb, kb, vt, Ebf, ao);

  // 4) O-proj + residual(x) -> t1 f32
  k_gemm<64, 8><<<dim3(16, 32), 256, 0, stream>>>(ao, Wot, bo, x, t1, 4096, 1024, 1024);

  // 5) LN1 -> o1f (f32) + o1b (bf16)
  k_layernorm<<<4096, 256, 0, stream>>>(t1, g1, be1, o1f, o1b);

  // 6) FFN1: relu(out1 @ W1 + b1) -> h1b bf16
  k_gemm<128, 3><<<dim3(32, 32), 256, 0, stream>>>(o1b, W1t, b1, nullptr, h1b, 4096, 4096, 1024);

  // 7) FFN2 + residual(o1f) -> d_out f32
  k_gemm<64, 8><<<dim3(16, 32), 256, 0, stream>>>(h1b, W2t, b2, o1f, outF, 4096, 1024, 4096);

  // 8) LN2 in-place on d_out
  k_layernorm<<<4096, 256, 0, stream>>>(outF, g2, be2, outF, nullptr);
}

// Round 7
// 344.739 us; speedup vs baseline: 2.0184x; 1.0514x over previous
//
#include <hip/hip_runtime.h>

typedef unsigned short u16;
typedef __attribute__((ext_vector_type(4))) short s16x4;
typedef __attribute__((ext_vector_type(8))) short s16x8;
typedef __attribute__((ext_vector_type(4))) float f32x4;

#define MFMA16(a,b,c) __builtin_amdgcn_mfma_f32_16x16x32_bf16((a),(b),(c),0,0,0)
#define LSEQ 2048
#define QSCALE 0.18033688011112042f  /* 0.125 * log2(e) */

__device__ __forceinline__ u16 f2b(float f) {
  union { float f; unsigned u; } v; v.f = f;
  unsigned r = v.u + 0x7FFFu + ((v.u >> 16) & 1u);
  return (u16)(r >> 16);
}
__device__ __forceinline__ void g2l16(const void* g, void* l) {
  __builtin_amdgcn_global_load_lds(
      (const __attribute__((address_space(1))) unsigned int*)g,
      (__attribute__((address_space(3))) unsigned int*)l, 16, 0, 0);
}

// ------------- fused prep: cvt(x), cvt(E), bias concat, 6 weight transposes -------------
// grid ranges: [0,1024) cvt x | [1024,1056) cvt E | 1056 bias | [1057,4129) transposes
__global__ __launch_bounds__(256) void k_prep_all(
    const float* __restrict__ x, const float* __restrict__ E,
    const float* __restrict__ bq, const float* __restrict__ bk, const float* __restrict__ bv,
    const float* __restrict__ Wq, const float* __restrict__ Wk, const float* __restrict__ Wv,
    const float* __restrict__ Wo, const float* __restrict__ W1, const float* __restrict__ W2,
    u16* __restrict__ xb, u16* __restrict__ Ebf, float* __restrict__ bcat,
    u16* __restrict__ Wqt, u16* __restrict__ Wot, u16* __restrict__ W1t, u16* __restrict__ W2t) {
  __shared__ float T[64][65];
  const int b = blockIdx.x, tid = threadIdx.x;

  if (b < 1056) {  // conversions
    const float* src = (b < 1024) ? x : E;
    u16* dst = (b < 1024) ? xb : Ebf;
    const int base = (b < 1024) ? b * 4096 : (b - 1024) * 4096;
#pragma unroll
    for (int p = 0; p < 4; p++) {
      int i = base + p * 1024 + tid * 4;
      float4 v = *(const float4*)(src + i);
      ushort4 o;
      o.x = f2b(v.x); o.y = f2b(v.y); o.z = f2b(v.z); o.w = f2b(v.w);
      *(ushort4*)(dst + i) = o;
    }
    return;
  }
  if (b == 1056) {  // bias concat
    for (int i = tid; i < 3072; i += 256)
      bcat[i] = (i < 1024) ? bq[i] : (i < 2048) ? bk[i - 1024] : bv[i - 2048];
    return;
  }

  // transposes: W[K,N] f32 -> Wt[N,K] bf16
  const int idx = b - 1057;
  const float* W; u16* Wt; int K, N, bx, by;
  if (idx < 1024) {
    const int m = idx >> 8, ti = idx & 255;
    const float* ws4[4] = {Wq, Wk, Wv, Wo};
    W = ws4[m];
    Wt = (m < 3) ? (Wqt + (size_t)m * 1048576) : Wot;
    K = 1024; N = 1024; bx = ti & 15; by = ti >> 4;
  } else if (idx < 2048) {
    const int ti = idx - 1024;
    W = W1; Wt = W1t; K = 1024; N = 4096; bx = ti & 63; by = ti >> 6;
  } else {
    const int ti = idx - 2048;
    W = W2; Wt = W2t; K = 4096; N = 1024; bx = ti & 15; by = ti >> 4;
  }
  const int k0 = by * 64, n0 = bx * 64;
  const int r = tid >> 4, c4 = (tid & 15) * 4;
#pragma unroll
  for (int i = 0; i < 4; i++) {
    float4 v = *(const float4*)(W + (size_t)(k0 + r + i * 16) * N + n0 + c4);
    T[r + i * 16][c4 + 0] = v.x; T[r + i * 16][c4 + 1] = v.y;
    T[r + i * 16][c4 + 2] = v.z; T[r + i * 16][c4 + 3] = v.w;
  }
  __syncthreads();
#pragma unroll
  for (int i = 0; i < 4; i++) {
    int nl = r + i * 16;
    ushort4 o;
    o.x = f2b(T[c4 + 0][nl]); o.y = f2b(T[c4 + 1][nl]);
    o.z = f2b(T[c4 + 2][nl]); o.w = f2b(T[c4 + 3][nl]);
    *(ushort4*)(Wt + (size_t)(n0 + nl) * K + k0 + c4) = o;
  }
}

// ------------- bf16 MFMA GEMM, gload_lds dbuf, swizzled LDS -------------
// FLAGS: 1=RELU, 2=BF16OUT, 4=QKV, 8=RESID_F32, 16=RESID_BF16
template <int BN, int FLAGS>
__global__ __launch_bounds__(256) void k_gemm(const u16* __restrict__ A, const u16* __restrict__ Bt,
                                              const float* __restrict__ bias, const void* __restrict__ resid,
                                              void* __restrict__ Cout, int M, int N, int K) {
  constexpr int MI = (BN == 128) ? 4 : 2;
  __shared__ __align__(16) u16 As[2][128 * 32];
  __shared__ __align__(16) u16 Bs[2][BN * 32];
  const int tid = threadIdx.x;
  const int lane = tid & 63, wave = tid >> 6;
  const int lo = lane & 15, hi = lane >> 4;
  const int WROW = (BN == 128) ? (wave >> 1) * 64 : wave * 32;
  const int WCOL = (BN == 128) ? (wave & 1) * 64 : 0;
  const int m0 = blockIdx.y * 128, n0 = blockIdx.x * BN;

  const int colg = ((lane & 3) * 16) ^ (((lane >> 3) & 3) << 4);
  const int arow = wave * 32 + (lane >> 2);
  const int swzr = ((lane >> 1) & 3) << 4;

  f32x4 acc[MI][4];
#pragma unroll
  for (int mi = 0; mi < MI; mi++)
#pragma unroll
    for (int ni = 0; ni < 4; ni++) acc[mi][ni] = (f32x4){0.f, 0.f, 0.f, 0.f};

  const char* Ab = (const char*)A;
  const char* Bb = (const char*)Bt;
  const int nt = K >> 5;

  auto stage = [&](int buf, int t) {
    const int k0 = t * 32;
    char* ad = (char*)&As[buf][0] + wave * 2048;
    const char* as = Ab + ((size_t)(m0 + arow) * K + k0) * 2 + colg;
    g2l16(as, ad);
    g2l16(as + (size_t)16 * K * 2, ad + 1024);
    if (BN == 128) {
      char* bd = (char*)&Bs[buf][0] + wave * 2048;
      const char* bs = Bb + ((size_t)(n0 + arow) * K + k0) * 2 + colg;
      g2l16(bs, bd);
      g2l16(bs + (size_t)16 * K * 2, bd + 1024);
    } else {
      char* bd = (char*)&Bs[buf][0] + wave * 1024;
      const int brow = wave * 16 + (lane >> 2);
      const char* bs = Bb + ((size_t)(n0 + brow) * K + k0) * 2 + colg;
      g2l16(bs, bd);
    }
  };

  stage(0, 0);
  int buf = 0;
  for (int t = 0; t < nt; t++) {
    __syncthreads();
    if (t + 1 < nt) stage(buf ^ 1, t + 1);
    const char* ab = (const char*)&As[buf][0];
    const char* bb2 = (const char*)&Bs[buf][0];
    s16x8 af[MI], bfr[4];
#pragma unroll
    for (int mi = 0; mi < MI; mi++) {
      int row = WROW + mi * 16 + lo;
      af[mi] = *(const s16x8*)(ab + row * 64 + ((hi * 16) ^ swzr));
    }
#pragma unroll
    for (int ni = 0; ni < 4; ni++) {
      int row = WCOL + ni * 16 + lo;
      bfr[ni] = *(const s16x8*)(bb2 + row * 64 + ((hi * 16) ^ swzr));
    }
#pragma unroll
    for (int mi = 0; mi < MI; mi++)
#pragma unroll
      for (int ni = 0; ni < 4; ni++)
        acc[mi][ni] = MFMA16(af[mi], bfr[ni], acc[mi][ni]);
    buf ^= 1;
  }

#pragma unroll
  for (int mi = 0; mi < MI; mi++)
#pragma unroll
    for (int ni = 0; ni < 4; ni++) {
      const int mb = m0 + WROW + mi * 16 + hi * 4;
      const int n = n0 + WCOL + ni * 16 + lo;
      float v4[4];
#pragma unroll
      for (int reg = 0; reg < 4; reg++) {
        float v = acc[mi][ni][reg] + bias[n];
        if (FLAGS & 8) v += ((const float*)resid)[(size_t)(mb + reg) * N + n];
        if (FLAGS & 16) {
          union { unsigned u; float f; } q;
          q.u = ((unsigned)((const u16*)resid)[(size_t)(mb + reg) * N + n]) << 16;
          v += q.f;
        }
        if (FLAGS & 1) v = fmaxf(v, 0.f);
        v4[reg] = v;
      }
      if (FLAGS & 4) {
        const int seg = n >> 10, nn = n & 1023;
        const int hh = nn >> 6, dd = nn & 63;
        const int bb = mb >> 11, ll = mb & 2047;
        u16* dst = (u16*)Cout + (size_t)seg * 4194304;
        if (seg == 0) {
#pragma unroll
          for (int reg = 0; reg < 4; reg++)
            dst[((size_t)(bb * 16 + hh) * LSEQ + ll + reg) * 64 + dd] = f2b(v4[reg] * QSCALE);
        } else if (seg == 1) {
#pragma unroll
          for (int reg = 0; reg < 4; reg++)
            dst[((size_t)(bb * 16 + hh) * LSEQ + ll + reg) * 64 + dd] = f2b(v4[reg]);
        } else {
          ushort4 o;
          o.x = f2b(v4[0]); o.y = f2b(v4[1]); o.z = f2b(v4[2]); o.w = f2b(v4[3]);
          *(ushort4*)&((u16*)dst)[((size_t)(bb * 16 + hh) * 64 + dd) * LSEQ + ll] = o;
        }
      } else if (FLAGS & 2) {
        u16* dst = (u16*)Cout;
#pragma unroll
        for (int reg = 0; reg < 4; reg++) dst[(size_t)(mb + reg) * N + n] = f2b(v4[reg]);
      } else {
        float* dst = (float*)Cout;
#pragma unroll
        for (int reg = 0; reg < 4; reg++) dst[(size_t)(mb + reg) * N + n] = v4[reg];
      }
    }
}

// ------------- fused rel-pos flash attention: transposed dataflow, 8 waves/block -------------
// 512-thread blocks, 128 query rows. S^T = mfma(K,Q): lane owns one query row, in-lane
// softmax w/ defer-max (THR=8), in-register P via v_cvt_pk_bf16_f32, K/V^T LDS-staged.
__global__ __launch_bounds__(512, 4) void k_attn(const u16* __restrict__ Qh, const u16* __restrict__ Kh,
                                                 const u16* __restrict__ Vt, const u16* __restrict__ Eb,
                                                 u16* __restrict__ Ob) {
  __shared__ __align__(16) u16 Ksh[2][64 * 64];
  __shared__ __align__(16) u16 Vts[2][64 * 64];
  __shared__ __align__(16) float Gsh[8][16 * 84];

  const int tid = threadIdx.x;
  const int lane = tid & 63, wave = tid >> 6;
  const int lo = lane & 15, hi = lane >> 4;

  const int hb = blockIdx.x;
  const int x = hb & 7;
  const int kk = hb >> 3;
  const int bh = x * 4 + (kk >> 4);
  const int ti = (kk & 32) ? (15 - (kk & 15)) : (kk & 15);
  const int l0 = ti * 128;
  const int bb = bh >> 4, hh = bh & 15;
  const int lw = l0 + wave * 16;

  const u16* Qb = Qh + (size_t)bh * LSEQ * 64;
  const char* Kb = (const char*)(Kh + (size_t)bh * LSEQ * 64);
  const char* Vb = (const char*)(Vt + (size_t)bh * 64 * LSEQ);

  const int colsw = ((lane & 7) * 16) ^ (((lane >> 3) & 7) << 4);
  const int swzv = (lo & 7) << 4;
  const int c0 = (hi * 16) ^ swzv;

  auto stageKV = [&](int buf_, int j0_) {
    char* kd = (char*)&Ksh[buf_][0] + wave * 1024;
    const char* ks = Kb + (size_t)(j0_ + wave * 8 + (lane >> 3)) * 128 + colsw;
    g2l16(ks, kd);
    char* vd = (char*)&Vts[buf_][0] + wave * 1024;
    const char* vs = Vb + (size_t)(wave * 8 + (lane >> 3)) * (LSEQ * 2) + (size_t)j0_ * 2 + colsw;
    g2l16(vs, vd);
  };

  s16x8 aq[2];
  aq[0] = *(const s16x8*)(Qb + (size_t)(lw + lo) * 64 + hi * 8);
  aq[1] = *(const s16x8*)(Qb + (size_t)(lw + lo) * 64 + 32 + hi * 8);

  float m_run = -1e30f, l_run = 0.f;
  f32x4 oacc[4];
#pragma unroll
  for (int f = 0; f < 4; f++) oacc[f] = (f32x4){0.f, 0.f, 0.f, 0.f};

  float* gw = &Gsh[wave][0];

  stageKV(0, 0);
  int buf = 0;

  for (int t = 0; t < 32; t++) {
    const int j0 = t * 64;
    const bool has_rel = (j0 <= lw);
    __syncthreads();
    if (t < 31) stageKV(buf ^ 1, j0 + 64);

    // S^T = mfma(K, Q)
    f32x4 s4[4];
#pragma unroll
    for (int c = 0; c < 4; c++) {
      const char* krow = (const char*)&Ksh[buf][0] + (c * 16 + lo) * 128;
      s16x8 a0 = *(const s16x8*)(krow + c0);
      s16x8 a1 = *(const s16x8*)(krow + (c0 ^ 64));
      s4[c] = (f32x4){0.f, 0.f, 0.f, 0.f};
      s4[c] = MFMA16(a0, aq[0], s4[c]);
      s4[c] = MFMA16(a1, aq[1], s4[c]);
    }

    // rel: G^T = mfma(E, Q), skew-gather through per-wave LDS
    if (has_rel) {
      const int waveBase = 2032 - lw + j0;
      const u16* ep0 = Eb + (size_t)(waveBase + lo) * 64 + hi * 8;
      s16x8 ec0 = *(const s16x8*)(ep0);
      s16x8 ec1 = *(const s16x8*)(ep0 + 32);
#pragma unroll
      for (int c2 = 0; c2 < 5; c2++) {
        s16x8 en0, en1;
        if (c2 < 4) {
          const u16* epn = ep0 + (size_t)(c2 + 1) * 16 * 64;
          en0 = *(const s16x8*)(epn);
          en1 = *(const s16x8*)(epn + 32);
        }
        f32x4 g = (f32x4){0.f, 0.f, 0.f, 0.f};
        g = MFMA16(ec0, aq[0], g);
        g = MFMA16(ec1, aq[1], g);
        *(f32x4*)(gw + 84 * lo + c2 * 16 + 4 * hi) = g;
        if (c2 < 4) { ec0 = en0; ec1 = en1; }
      }
      const int dd = lw - j0;
      if (dd >= 64) {
#pragma unroll
        for (int c = 0; c < 4; c++)
#pragma unroll
          for (int reg = 0; reg < 4; reg++)
            s4[c][reg] += gw[83 * lo + 15 + c * 16 + 4 * hi + reg];
      } else {
        const int rmax = dd + lo;
#pragma unroll
        for (int c = 0; c < 4; c++)
#pragma unroll
          for (int reg = 0; reg < 4; reg++) {
            int jr = c * 16 + 4 * hi + reg;
            float g = gw[83 * lo + 15 + jr];
            s4[c][reg] += (jr <= rmax) ? g : 0.f;
          }
      }
    }

    // V A-frags from LDS (permuted k-slots)
    s16x4 vA[4][2], vB2[4][2];
#pragma unroll
    for (int f = 0; f < 4; f++) {
      const char* vrow = (const char*)&Vts[buf][0] + (f * 16 + lo) * 128;
#pragma unroll
      for (int m = 0; m < 2; m++) {
        vA[f][m]  = *(const s16x4*)(vrow + ((64 * m + 8 * hi) ^ swzv));
        vB2[f][m] = *(const s16x4*)(vrow + ((64 * m + 8 * hi + 32) ^ swzv));
      }
    }

    // in-lane softmax (base-2) with defer-max (THR=8)
    float mta = fmaxf(fmaxf(fmaxf(s4[0][0], s4[0][1]), fmaxf(s4[0][2], s4[0][3])),
                      fmaxf(fmaxf(s4[1][0], s4[1][1]), fmaxf(s4[1][2], s4[1][3])));
    float mtb = fmaxf(fmaxf(fmaxf(s4[2][0], s4[2][1]), fmaxf(s4[2][2], s4[2][3])),
                      fmaxf(fmaxf(s4[3][0], s4[3][1]), fmaxf(s4[3][2], s4[3][3])));
    float mt = fmaxf(mta, mtb);
    mt = fmaxf(mt, __shfl_xor(mt, 16, 64));
    mt = fmaxf(mt, __shfl_xor(mt, 32, 64));
    if (!__all(mt - m_run <= 8.f)) {
      float mnew = fmaxf(m_run, mt);
      float scl = exp2f(m_run - mnew);
      m_run = mnew;
      l_run *= scl;
#pragma unroll
      for (int f = 0; f < 4; f++)
#pragma unroll
        for (int reg = 0; reg < 4; reg++) oacc[f][reg] *= scl;
    }

    unsigned w8[8];
    float psum = 0.f;
#pragma unroll
    for (int c = 0; c < 4; c++) {
      float a0 = exp2f(s4[c][0] - m_run), a1 = exp2f(s4[c][1] - m_run);
      float a2 = exp2f(s4[c][2] - m_run), a3 = exp2f(s4[c][3] - m_run);
      psum += (a0 + a1) + (a2 + a3);
      asm("v_cvt_pk_bf16_f32 %0, %1, %2" : "=v"(w8[c * 2]) : "v"(a0), "v"(a1));
      asm("v_cvt_pk_bf16_f32 %0, %1, %2" : "=v"(w8[c * 2 + 1]) : "v"(a2), "v"(a3));
    }

    union UU { uint4 u; s16x8 v; };
    UU pb0, pb1;
    pb0.u = make_uint4(w8[0], w8[1], w8[2], w8[3]);
    pb1.u = make_uint4(w8[4], w8[5], w8[6], w8[7]);

    // O^T += V^T · P
#pragma unroll
    for (int f = 0; f < 4; f++) {
      s16x8 v0 = __builtin_shufflevector(vA[f][0], vB2[f][0], 0, 1, 2, 3, 4, 5, 6, 7);
      s16x8 v1 = __builtin_shufflevector(vA[f][1], vB2[f][1], 0, 1, 2, 3, 4, 5, 6, 7);
      oacc[f] = MFMA16(v0, pb0.v, oacc[f]);
      oacc[f] = MFMA16(v1, pb1.v, oacc[f]);
    }

    psum += __shfl_xor(psum, 16, 64);
    psum += __shfl_xor(psum, 32, 64);
    l_run += psum;

    buf ^= 1;
  }

  const float inv = 1.f / l_run;
  const size_t orow = (size_t)(bb * LSEQ + lw + lo) * 1024 + hh * 64;
#pragma unroll
  for (int f = 0; f < 4; f++) {
    ushort4 o;
    o.x = f2b(oacc[f][0] * inv); o.y = f2b(oacc[f][1] * inv);
    o.z = f2b(oacc[f][2] * inv); o.w = f2b(oacc[f][3] * inv);
    *(ushort4*)(Ob + orow + f * 16 + 4 * hi) = o;
  }
}

// ------------- LayerNorm over rows of 1024; f32 and/or bf16 out -------------
__global__ __launch_bounds__(256) void k_layernorm(const float* __restrict__ X, const float* __restrict__ gw,
                                                   const float* __restrict__ bw, float* __restrict__ outF,
                                                   u16* __restrict__ outB) {
  __shared__ float red[2][4];
  const int row = blockIdx.x, tid = threadIdx.x;
  const int lane = tid & 63, wave = tid >> 6;
  const float* x = X + (size_t)row * 1024;
  float4 v = *(const float4*)(x + tid * 4);
  float s = v.x + v.y + v.z + v.w;
  float s2 = v.x * v.x + v.y * v.y + v.z * v.z + v.w * v.w;
#pragma unroll
  for (int msk = 1; msk <= 32; msk <<= 1) {
    s += __shfl_xor(s, msk, 64);
    s2 += __shfl_xor(s2, msk, 64);
  }
  if (lane == 0) { red[0][wave] = s; red[1][wave] = s2; }
  __syncthreads();
  s = red[0][0] + red[0][1] + red[0][2] + red[0][3];
  s2 = red[1][0] + red[1][1] + red[1][2] + red[1][3];
  float mean = s * (1.f / 1024.f);
  float var = s2 * (1.f / 1024.f) - mean * mean;
  float rs = rsqrtf(var + 1e-6f);
  float4 g4 = *(const float4*)(gw + tid * 4);
  float4 b4 = *(const float4*)(bw + tid * 4);
  float4 o;
  o.x = (v.x - mean) * rs * g4.x + b4.x;
  o.y = (v.y - mean) * rs * g4.y + b4.y;
  o.z = (v.z - mean) * rs * g4.z + b4.z;
  o.w = (v.w - mean) * rs * g4.w + b4.w;
  if (outF) *(float4*)(outF + (size_t)row * 1024 + tid * 4) = o;
  if (outB) {
    ushort4 ob;
    ob.x = f2b(o.x); ob.y = f2b(o.y); ob.z = f2b(o.z); ob.w = f2b(o.w);
    *(ushort4*)(outB + (size_t)row * 1024 + tid * 4) = ob;
  }
}

extern "C" void kernel_launch(void* const* d_in, const int* in_sizes, int n_in,
                              void* d_out, int out_size, void* d_ws, size_t ws_size,
                              hipStream_t stream) {
  const float* x   = (const float*)d_in[0];
  const float* Wq  = (const float*)d_in[1];
  const float* bq  = (const float*)d_in[2];
  const float* Wk  = (const float*)d_in[3];
  const float* bk  = (const float*)d_in[4];
  const float* Wv  = (const float*)d_in[5];
  const float* bv  = (const float*)d_in[6];
  const float* Wo  = (const float*)d_in[7];
  const float* bo  = (const float*)d_in[8];
  const float* E   = (const float*)d_in[9];
  const float* W1  = (const float*)d_in[10];
  const float* b1  = (const float*)d_in[11];
  const float* W2  = (const float*)d_in[12];
  const float* b2  = (const float*)d_in[13];
  const float* g1  = (const float*)d_in[14];
  const float* be1 = (const float*)d_in[15];
  const float* g2  = (const float*)d_in[16];
  const float* be2 = (const float*)d_in[17];

  char* ws = (char*)d_ws;
  const size_t MB = 1ull << 20;
  u16* Wqt = (u16*)(ws + 0 * MB);          // 6MB contiguous [3072][1024]
  u16* Wot = (u16*)(ws + 6 * MB);          // 2MB
  u16* W1t = (u16*)(ws + 8 * MB);          // 8MB [4096][1024]
  u16* W2t = (u16*)(ws + 16 * MB);         // 8MB [1024][4096]
  u16* Ebf = (u16*)(ws + 24 * MB);         // 256KB (+ slack for OOB band reads)
  float* bcat = (float*)(ws + 24 * MB + 512 * 1024);  // 12KB
  u16* xb  = (u16*)(ws + 25 * MB);         // 8MB [4096][1024]
  u16* qb  = (u16*)(ws + 33 * MB);         // 8MB head-major (QSCALE'd)
  u16* kb  = (u16*)(ws + 41 * MB);         // 8MB head-major
  u16* vt  = (u16*)(ws + 49 * MB);         // 8MB [bh][64][L]
  u16* ao  = (u16*)(ws + 57 * MB);         // 8MB [4096][1024]
  float* t1 = (float*)(ws + 65 * MB);      // 16MB f32
  u16* o1b  = (u16*)(ws + 25 * MB);        // reuse xb
  u16* h1b  = (u16*)(ws + 49 * MB);        // reuse vt/ao/t1, 32MB
  float* outF = (float*)d_out;

  // 1) fused prep (1 launch): cvt x, cvt E, bias concat, 6 transposes
  k_prep_all<<<4129, 256, 0, stream>>>(x, E, bq, bk, bv, Wq, Wk, Wv, Wo, W1, W2,
                                       xb, Ebf, bcat, Wqt, Wot, W1t, W2t);

  // 2) fused QKV projection (writes qb, kb, vt)
  k_gemm<128, 4><<<dim3(24, 32), 256, 0, stream>>>(xb, Wqt, bcat, nullptr, qb, 4096, 3072, 1024);

  // 3) rel-pos flash attention -> ao
  k_attn<<<dim3(512), 512, 0, stream>>>(qb, kb, vt, Ebf, ao);

  // 4) O-proj + residual(x, f32) -> t1
  k_gemm<64, 8><<<dim3(16, 32), 256, 0, stream>>>(ao, Wot, bo, x, t1, 4096, 1024, 1024);

  // 5) LN1 -> o1b (bf16 only)
  k_layernorm<<<4096, 256, 0, stream>>>(t1, g1, be1, nullptr, o1b);

  // 6) FFN1: relu(o1 @ W1 + b1) -> h1b bf16
  k_gemm<128, 3><<<dim3(32, 32), 256, 0, stream>>>(o1b, W1t, b1, nullptr, h1b, 4096, 4096, 1024);

  // 7) FFN2 + residual(o1b, bf16) -> d_out f32
  k_gemm<64, 16><<<dim3(16, 32), 256, 0, stream>>>(h1b, W2t, b2, o1b, outF, 4096, 1024, 4096);

  // 8) LN2 in-place on d_out
  k_layernorm<<<4096, 256, 0, stream>>>(outF, g2, be2, outF, nullptr);
}